// Round 19
// baseline (188.397 us; speedup 1.0000x reference)
//
#include <hip/hip_runtime.h>
#include <hip/hip_bf16.h>

// ---- problem constants ----
#define HIDN 1536
#define NH   24
#define NKV  6
#define HD   64
#define BB   2
#define SS   2048
#define MTOT (BB*SS)   // 4096
#define NQKV 2304      // NH*HD + 2*NKV*HD
#define NCHUNK 68      // sum over qt=0..31 of ceil((qt+1)/10): 10 + 20 + 30 + 8
#define LOG2E 1.4426950408889634f

typedef __bf16 bf16x8 __attribute__((ext_vector_type(8)));
typedef float  f32x4  __attribute__((ext_vector_type(4)));
typedef unsigned short u16x8 __attribute__((ext_vector_type(8)));
typedef unsigned int   u32x2 __attribute__((ext_vector_type(2)));

typedef __attribute__((address_space(1))) const unsigned short as1_ushort;
typedef __attribute__((address_space(3))) unsigned short as3_ushort;

__device__ inline float bf2f(unsigned short u) {
    unsigned v = (unsigned)u << 16; float f; __builtin_memcpy(&f, &v, 4); return f;
}
__device__ inline unsigned short f2bf(float f) {
    unsigned u; __builtin_memcpy(&u, &f, 4);
    u = (u + 0x7FFFu + ((u >> 16) & 1u)) >> 16;
    return (unsigned short)u;
}
__device__ inline unsigned cvt_pk_bf16(float lo, float hi) {
    unsigned r;
    asm("v_cvt_pk_bf16_f32 %0, %1, %2" : "=v"(r) : "v"(lo), "v"(hi));
    return r;
}
// bare hardware 2^x (no libm fixup)
__device__ inline float exp2_hw(float x) {
    float r;
    asm("v_exp_f32 %0, %1" : "=v"(r) : "v"(x));
    return r;
}
// all-reduce max within each 16-lane DPP row via row_ror rotations (VALU-speed)
__device__ inline float rowmax16_dpp(float x) {
    int v, r;
    v = __float_as_int(x);
    r = __builtin_amdgcn_update_dpp(v, v, 0x121, 0xF, 0xF, false);  // row_ror:1
    x = fmaxf(x, __int_as_float(r));
    v = __float_as_int(x);
    r = __builtin_amdgcn_update_dpp(v, v, 0x122, 0xF, 0xF, false);  // row_ror:2
    x = fmaxf(x, __int_as_float(r));
    v = __float_as_int(x);
    r = __builtin_amdgcn_update_dpp(v, v, 0x124, 0xF, 0xF, false);  // row_ror:4
    x = fmaxf(x, __int_as_float(r));
    v = __float_as_int(x);
    r = __builtin_amdgcn_update_dpp(v, v, 0x128, 0xF, 0xF, false);  // row_ror:8
    x = fmaxf(x, __int_as_float(r));
    return x;
}

// XCD-chunked bijective block swizzle (requires nwg % 8 == 0):
// same-XCD blocks become consecutive in row-major order -> A/B panel L2 locality.
__device__ inline void xcd_swizzle(int& bx, int& by) {
    int gx = gridDim.x;
    int nwg = gx * gridDim.y;
    int flat = (int)blockIdx.y * gx + (int)blockIdx.x;
    int cpx = nwg >> 3;
    int swz = (flat & 7) * cpx + (flat >> 3);
    bx = swz % gx;
    by = swz / gx;
}

// ---------- merged prep: hidden cast + 4 weight casts + RoPE table ----------
__global__ __launch_bounds__(256) void k_prep(const float* __restrict__ h_f,
                                              const float* __restrict__ Wq,
                                              const float* __restrict__ Wk,
                                              const float* __restrict__ Wv,
                                              const float* __restrict__ Wo,
                                              unsigned short* __restrict__ h_bf,
                                              unsigned short* __restrict__ qkv_w,
                                              unsigned short* __restrict__ Wo_bf,
                                              float2* __restrict__ cs) {
    int i = blockIdx.x * 256 + threadIdx.x;
    const int nH = MTOT * HIDN / 4;        // 1572864
    const int nQ = HIDN * HIDN / 4;        // 589824
    const int nK = NKV * HD * HIDN / 4;    // 147456
    const int nW = 2 * nQ + 2 * nK;        // 1474560
    if (i < nH + nW) {
        const float* src; unsigned short* dst; int j;
        if (i < nH)                    { src = h_f; dst = h_bf;                        j = i; }
        else if ((i -= nH) < nQ)       { src = Wq;  dst = qkv_w;                       j = i; }
        else if (i < nQ + nK)          { src = Wk;  dst = qkv_w + (size_t)nQ * 4;      j = i - nQ; }
        else if (i < nQ + 2 * nK)      { src = Wv;  dst = qkv_w + (size_t)(nQ + nK) * 4; j = i - nQ - nK; }
        else                           { src = Wo;  dst = Wo_bf;                       j = i - nQ - 2 * nK; }
        float4 v = reinterpret_cast<const float4*>(src)[j];
        ushort4 o;
        o.x = f2bf(v.x); o.y = f2bf(v.y); o.z = f2bf(v.z); o.w = f2bf(v.w);
        reinterpret_cast<ushort4*>(dst)[j] = o;
        return;
    }
    int k = i - (nH + nW);
    if (k < SS * 32) {
        int s = k >> 5, f = k & 31;
        double inv = pow(10000.0, -(double)f / 32.0);
        double ang = (double)s * inv;
        cs[k] = make_float2((float)cos(ang), (float)sin(ang));
    }
}

// ---------- GEMM, BK=64, XOR-swizzled LDS, double-buffered, XCD-swizzled grid ----------
template <typename OutT>
__global__ __launch_bounds__(256) void gemm_bt(const unsigned short* __restrict__ A,
                                               const unsigned short* __restrict__ Bt,
                                               OutT* __restrict__ C,
                                               int N, int K) {
    __shared__ unsigned short Alds[2][128 * 64];   // 2 x 16KB
    __shared__ unsigned short Blds[2][128 * 64];   // 2 x 16KB
    int t = threadIdx.x;
    int lane = t & 63, w = t >> 6;
    int bx, by;
    xcd_swizzle(bx, by);
    int m0 = by * 128, n0 = bx * 128;
    int wm = (w >> 1) * 64, wn = (w & 1) * 64;
    int cidx = lane & 15, quad = lane >> 4;
    int srow = lane >> 3, scol = (lane & 7) * 8;

    int srcoff[4], dstoff[4];
#pragma unroll
    for (int c = 0; c < 4; ++c) {
        int chunk = w + c * 4;
        int row = chunk * 8 + srow;
        int col = scol ^ ((row & 7) * 8);
        srcoff[c] = row * K + col;
        dstoff[c] = chunk * 512;
    }

    f32x4 zero = {0.f, 0.f, 0.f, 0.f};
    f32x4 acc[4][4];
#pragma unroll
    for (int mi = 0; mi < 4; ++mi)
#pragma unroll
        for (int ni = 0; ni < 4; ++ni) acc[mi][ni] = zero;

    const unsigned short* Ab = A + (size_t)m0 * K;
    const unsigned short* Bb = Bt + (size_t)n0 * K;

#pragma unroll
    for (int c = 0; c < 4; ++c) {
        __builtin_amdgcn_global_load_lds((as1_ushort*)(Ab + srcoff[c]),
                                         (as3_ushort*)&Alds[0][dstoff[c]], 16, 0, 0);
        __builtin_amdgcn_global_load_lds((as1_ushort*)(Bb + srcoff[c]),
                                         (as3_ushort*)&Blds[0][dstoff[c]], 16, 0, 0);
    }
    asm volatile("s_waitcnt vmcnt(0)" ::: "memory");
    __syncthreads();

    int nk = K >> 6;
    for (int kt = 0; kt < nk; ++kt) {
        int cur = kt & 1;
        if (kt + 1 < nk) {
            int koff = (kt + 1) * 64;
#pragma unroll
            for (int c = 0; c < 4; ++c) {
                __builtin_amdgcn_global_load_lds((as1_ushort*)(Ab + srcoff[c] + koff),
                                                 (as3_ushort*)&Alds[cur ^ 1][dstoff[c]], 16, 0, 0);
                __builtin_amdgcn_global_load_lds((as1_ushort*)(Bb + srcoff[c] + koff),
                                                 (as3_ushort*)&Blds[cur ^ 1][dstoff[c]], 16, 0, 0);
            }
        }
#pragma unroll
        for (int ka = 0; ka < 2; ++ka) {
            bf16x8 af[4], bfr[4];
#pragma unroll
            for (int mi = 0; mi < 4; ++mi) {
                int arow = wm + mi * 16 + cidx;
                af[mi] = *reinterpret_cast<bf16x8*>(
                    &Alds[cur][arow * 64 + ((ka * 32 + quad * 8) ^ ((arow & 7) * 8))]);
            }
#pragma unroll
            for (int ni = 0; ni < 4; ++ni) {
                int brow = wn + ni * 16 + cidx;
                bfr[ni] = *reinterpret_cast<bf16x8*>(
                    &Blds[cur][brow * 64 + ((ka * 32 + quad * 8) ^ ((brow & 7) * 8))]);
            }
#pragma unroll
            for (int mi = 0; mi < 4; ++mi)
#pragma unroll
                for (int ni = 0; ni < 4; ++ni)
                    acc[mi][ni] = __builtin_amdgcn_mfma_f32_16x16x32_bf16(af[mi], bfr[ni],
                                                                          acc[mi][ni], 0, 0, 0);
        }
        asm volatile("s_waitcnt vmcnt(0)" ::: "memory");
        __syncthreads();
    }
#pragma unroll
    for (int mi = 0; mi < 4; ++mi)
#pragma unroll
        for (int ni = 0; ni < 4; ++ni)
#pragma unroll
            for (int i = 0; i < 4; ++i) {
                int row = m0 + wm + mi * 16 + quad * 4 + i;
                int col = n0 + wn + ni * 16 + cidx;
                C[(size_t)row * N + col] = acc[mi][ni][i];
            }
}

// ---------- fused QKV GEMM (BK=64, swizzled, double-buffered, XCD-swizzled) ----------
__global__ __launch_bounds__(256) void gemm_qkv(const unsigned short* __restrict__ A,
                                                const unsigned short* __restrict__ Bt,
                                                const int* __restrict__ pos_ids,
                                                const float2* __restrict__ cs,
                                                unsigned short* __restrict__ q_p,
                                                unsigned short* __restrict__ k_p,
                                                unsigned short* __restrict__ v_p) {
    __shared__ unsigned short Alds[2][128 * 64];
    __shared__ unsigned short Blds[2][128 * 64];
    int t = threadIdx.x;
    int lane = t & 63, w = t >> 6;
    int bx, by;
    xcd_swizzle(bx, by);
    int m0 = by * 128, n0 = bx * 128;
    int wm = (w >> 1) * 64, wn = (w & 1) * 64;
    int cidx = lane & 15, quad = lane >> 4;
    int srow = lane >> 3, scol = (lane & 7) * 8;

    int srcoff[4], dstoff[4];
#pragma unroll
    for (int c = 0; c < 4; ++c) {
        int chunk = w + c * 4;
        int row = chunk * 8 + srow;
        int col = scol ^ ((row & 7) * 8);
        srcoff[c] = row * HIDN + col;
        dstoff[c] = chunk * 512;
    }

    f32x4 zero = {0.f, 0.f, 0.f, 0.f};
    f32x4 acc[4][4];
#pragma unroll
    for (int mi = 0; mi < 4; ++mi)
#pragma unroll
        for (int ni = 0; ni < 4; ++ni) acc[mi][ni] = zero;

    const unsigned short* Ab = A + (size_t)m0 * HIDN;
    const unsigned short* Bb = Bt + (size_t)n0 * HIDN;

#pragma unroll
    for (int c = 0; c < 4; ++c) {
        __builtin_amdgcn_global_load_lds((as1_ushort*)(Ab + srcoff[c]),
                                         (as3_ushort*)&Alds[0][dstoff[c]], 16, 0, 0);
        __builtin_amdgcn_global_load_lds((as1_ushort*)(Bb + srcoff[c]),
                                         (as3_ushort*)&Blds[0][dstoff[c]], 16, 0, 0);
    }
    asm volatile("s_waitcnt vmcnt(0)" ::: "memory");
    __syncthreads();

    const int nk = HIDN >> 6;
    for (int kt = 0; kt < nk; ++kt) {
        int cur = kt & 1;
        if (kt + 1 < nk) {
            int koff = (kt + 1) * 64;
#pragma unroll
            for (int c = 0; c < 4; ++c) {
                __builtin_amdgcn_global_load_lds((as1_ushort*)(Ab + srcoff[c] + koff),
                                                 (as3_ushort*)&Alds[cur ^ 1][dstoff[c]], 16, 0, 0);
                __builtin_amdgcn_global_load_lds((as1_ushort*)(Bb + srcoff[c] + koff),
                                                 (as3_ushort*)&Blds[cur ^ 1][dstoff[c]], 16, 0, 0);
            }
        }
#pragma unroll
        for (int ka = 0; ka < 2; ++ka) {
            bf16x8 af[4], bfr[4];
#pragma unroll
            for (int mi = 0; mi < 4; ++mi) {
                int arow = wm + mi * 16 + cidx;
                af[mi] = *reinterpret_cast<bf16x8*>(
                    &Alds[cur][arow * 64 + ((ka * 32 + quad * 8) ^ ((arow & 7) * 8))]);
            }
#pragma unroll
            for (int ni = 0; ni < 4; ++ni) {
                int brow = wn + ni * 16 + cidx;
                bfr[ni] = *reinterpret_cast<bf16x8*>(
                    &Blds[cur][brow * 64 + ((ka * 32 + quad * 8) ^ ((brow & 7) * 8))]);
            }
#pragma unroll
            for (int mi = 0; mi < 4; ++mi)
#pragma unroll
                for (int ni = 0; ni < 4; ++ni)
                    acc[mi][ni] = __builtin_amdgcn_mfma_f32_16x16x32_bf16(af[mi], bfr[ni],
                                                                          acc[mi][ni], 0, 0, 0);
        }
        asm volatile("s_waitcnt vmcnt(0)" ::: "memory");
        __syncthreads();
    }

    // ---- fused epilogue ----
    int colbase = n0 + wn;   // multiple of 64 -> exactly one head
    if (colbase >= NH * HD + NKV * HD) {        // V segment: plain pack
        int h = (colbase - (NH * HD + NKV * HD)) >> 6;
#pragma unroll
        for (int mi = 0; mi < 4; ++mi)
#pragma unroll
            for (int i = 0; i < 4; ++i) {
                int row = m0 + wm + mi * 16 + quad * 4 + i;
                int b = row >> 11, s = row & 2047;
                size_t base = ((size_t)(b * NKV + h) * SS + s) * 64;
#pragma unroll
                for (int ni = 0; ni < 4; ++ni)
                    v_p[base + ni * 16 + cidx] = f2bf(acc[mi][ni][i]);
            }
    } else {
        bool isQ = colbase < NH * HD;
        unsigned short* dst = isQ ? q_p : k_p;
        int h = isQ ? (colbase >> 6) : ((colbase - NH * HD) >> 6);
        int H = isQ ? NH : NKV;
        float scl = isQ ? (0.125f * LOG2E) : 1.0f;  // Q pre-scaled; log2-domain softmax
#pragma unroll
        for (int mi = 0; mi < 4; ++mi)
#pragma unroll
            for (int i = 0; i < 4; ++i) {
                int row = m0 + wm + mi * 16 + quad * 4 + i;
                int b = row >> 11, s = row & 2047;
                int pos = pos_ids[row];
                float2 c1 = cs[pos * 32 + cidx];
                float2 c2 = cs[pos * 32 + 16 + cidx];
                size_t base = ((size_t)(b * H + h) * SS + s) * 64;
                float x10 = acc[mi][0][i], x20 = acc[mi][2][i];
                float x11 = acc[mi][1][i], x21 = acc[mi][3][i];
                dst[base + cidx]       = f2bf((x10 * c1.x - x20 * c1.y) * scl);
                dst[base + 32 + cidx]  = f2bf((x20 * c1.x + x10 * c1.y) * scl);
                dst[base + 16 + cidx]  = f2bf((x11 * c2.x - x21 * c2.y) * scl);
                dst[base + 48 + cidx]  = f2bf((x21 * c2.x + x11 * c2.y) * scl);
            }
    }
}

// ---------- split-KV flash attention: chunks of <=10 tiles, balanced split ----------
// C(qt)=ceil((qt+1)/10) in {1,2,3,4}; NCHUNK=68. qt<10: single chunk, direct write.
// Chunk c covers tiles [c*ntot/C, (c+1)*ntot/C).
#define TRR(dst, ADDR, OFF) asm volatile("ds_read_b64_tr_b16 %0, %1 offset:" #OFF \
                                         : "=v"(dst) : "v"(ADDR))

__global__ __launch_bounds__(256, 4) void k_attn(const unsigned short* __restrict__ Qp,
                                                 const unsigned short* __restrict__ Kp,
                                                 const unsigned short* __restrict__ Vp,
                                                 unsigned short* __restrict__ part_acc,
                                                 float* __restrict__ part_ml,
                                                 unsigned short* __restrict__ a_out) {
    int bxr = NCHUNK - 1 - (int)blockIdx.x;   // heavy (large qt) first
    int h = blockIdx.y, b = blockIdx.z;
    int kvh = h >> 2;
    // decode bxr -> (g, qt, c): g0: qt 0..9 (10), g1: qt 10..19 x2 (20),
    // g2: qt 20..29 x3 (30), g3: qt 30..31 x4 (8)
    int g, qt, c;
    if (bxr < 10)      { g = 0; qt = bxr; c = 0; }
    else if (bxr < 30) { g = 1; int idx = bxr - 10; qt = 10 + (idx >> 1); c = idx & 1; }
    else if (bxr < 60) { g = 2; int idx = bxr - 30; qt = 20 + idx / 3; c = idx % 3; }
    else               { g = 3; int idx = bxr - 60; qt = 30 + (idx >> 2); c = idx & 3; }
    int p = (b * NH + h) * NCHUNK + bxr;
    int qbase = qt * 64;
    int ntot = qt + 1, C = g + 1;
    int t0 = c * ntot / C;
    int nt = (c + 1) * ntot / C - t0;
    int ck0 = t0 * 64;

    int t = threadIdx.x, lane = t & 63, w = t >> 6;
    int cidx = lane & 15, quad = lane >> 4;
    int qrow0 = qbase + w * 16;

    const unsigned short* qptr  = Qp + ((size_t)(b * NH + h) * SS + qrow0) * HD;
    const unsigned short* kbase = Kp + (((size_t)(b * NKV + kvh) * SS) + ck0) * HD;
    const unsigned short* vbase = Vp + (((size_t)(b * NKV + kvh) * SS) + ck0) * HD;

    __shared__ unsigned short Klds[2 * 4096];    // 2 x 8KB tiled K [ht][ka][quad][cidx][8]
    __shared__ unsigned short Vt[2 * 4096];      // 2 x 8KB tiled V [d16][kv4][4][16]
    __shared__ unsigned short Pt[4][64 * 16];    // per-wave P^T

    const unsigned short* ksrc[2];
    const unsigned short* vsrc[2];
#pragma unroll
    for (int i = 0; i < 2; ++i) {
        int o = (w * 2 + i) * 512 + lane * 8;
        int kh = o >> 10, ka_ = (o >> 9) & 1, kq = (o >> 7) & 3, kc = (o >> 3) & 15;
        ksrc[i] = kbase + (kh * 16 + kc) * HD + ka_ * 32 + kq * 8;
        int r = o & 1023;
        int kv = ((r >> 6) << 2) | ((r >> 4) & 3);
        int d  = ((o >> 10) << 4) | (r & 15);
        vsrc[i] = vbase + kv * HD + d;
    }

    bf16x8 qa[2];
#pragma unroll
    for (int ka = 0; ka < 2; ++ka)
        qa[ka] = *reinterpret_cast<const bf16x8*>(qptr + (size_t)cidx * HD + ka * 32 + quad * 8);

    bf16x8 ones;
    {
        unsigned short ob = 0x3F80;  // bf16 1.0
        u16x8 ov;
#pragma unroll
        for (int j = 0; j < 8; ++j) ov[j] = ob;
        __builtin_memcpy(&ones, &ov, 16);
    }

    f32x4 zero = {0.f, 0.f, 0.f, 0.f};
    f32x4 acc[4], acc_l = zero;
    float m_run[4];
#pragma unroll
    for (int i = 0; i < 4; ++i) { acc[i] = zero; m_run[i] = -1e30f; }

    // prologue: stage K0,V0 into buf 0
#pragma unroll
    for (int i = 0; i < 2; ++i) {
        __builtin_amdgcn_global_load_lds((as1_ushort*)ksrc[i],
                                         (as3_ushort*)&Klds[(w * 2 + i) * 512], 16, 0, 0);
        __builtin_amdgcn_global_load_lds((as1_ushort*)vsrc[i],
                                         (as3_ushort*)&Vt[(w * 2 + i) * 512], 16, 0, 0);
    }
    asm volatile("s_waitcnt vmcnt(0)" ::: "memory");
    __syncthreads();

    unsigned vtb  = (unsigned)(uintptr_t)(as3_ushort*)&Vt[0];
    unsigned va_base = vtb + (unsigned)(quad * 256 + cidx * 8);
    unsigned ptb  = (unsigned)(uintptr_t)(as3_ushort*)&Pt[w][0];
    unsigned va_p = ptb + (unsigned)(quad * 256 + cidx * 8);
    char* pwr = (char*)&Pt[w][0] + cidx * 32 + quad * 8;

    for (int it = 0; it < nt; ++it) {
        int cur = it & 1;
        int kvb = ck0 + it * 64;

        // ---- issue next-tile K+V prefetch ----
        if (it + 1 < nt) {
            size_t nv = (size_t)(it + 1) * 64 * HD;
#pragma unroll
            for (int i = 0; i < 2; ++i) {
                __builtin_amdgcn_global_load_lds(
                    (as1_ushort*)(ksrc[i] + nv),
                    (as3_ushort*)&Klds[(cur ^ 1) * 4096 + (w * 2 + i) * 512], 16, 0, 0);
                __builtin_amdgcn_global_load_lds(
                    (as1_ushort*)(vsrc[i] + nv),
                    (as3_ushort*)&Vt[(cur ^ 1) * 4096 + (w * 2 + i) * 512], 16, 0, 0);
            }
        }

        // ---- QK^T from LDS ----
        bf16x8 kb[4][2];
#pragma unroll
        for (int ht = 0; ht < 4; ++ht)
#pragma unroll
            for (int ka = 0; ka < 2; ++ka)
                kb[ht][ka] = *reinterpret_cast<bf16x8*>(
                    &Klds[cur * 4096 + ht * 1024 + ka * 512 + quad * 128 + cidx * 8]);
        f32x4 sc[4];
#pragma unroll
        for (int ht = 0; ht < 4; ++ht) {
            f32x4 cacc = zero;
            cacc = __builtin_amdgcn_mfma_f32_16x16x32_bf16(qa[0], kb[ht][0], cacc, 0, 0, 0);
            cacc = __builtin_amdgcn_mfma_f32_16x16x32_bf16(qa[1], kb[ht][1], cacc, 0, 0, 0);
            sc[ht] = cacc;
        }

        // ---- V tr-reads hoisted (V[cur] drained last iter; latency hides under softmax) ----
        unsigned va = va_base + (unsigned)(cur * 8192);
        u32x2 tv[4][4];
        TRR(tv[0][0], va, 0);    TRR(tv[0][1], va, 128);
        TRR(tv[0][2], va, 1024); TRR(tv[0][3], va, 1152);
        TRR(tv[1][0], va, 2048); TRR(tv[1][1], va, 2176);
        TRR(tv[1][2], va, 3072); TRR(tv[1][3], va, 3200);
        TRR(tv[2][0], va, 4096); TRR(tv[2][1], va, 4224);
        TRR(tv[2][2], va, 5120); TRR(tv[2][3], va, 5248);
        TRR(tv[3][0], va, 6144); TRR(tv[3][1], va, 6272);
        TRR(tv[3][2], va, 7168); TRR(tv[3][3], va, 7296);

        // ---- causal mask (diagonal tile only) ----
        if (kvb + 63 > qrow0) {
#pragma unroll
            for (int ht = 0; ht < 4; ++ht)
#pragma unroll
                for (int i = 0; i < 4; ++i)
                    if (kvb + ht * 16 + cidx > qrow0 + quad * 4 + i) sc[ht][i] = -1e30f;
        }

        // ---- row max via DPP rotations ----
        float mx[4];
#pragma unroll
        for (int i = 0; i < 4; ++i) {
            mx[i] = fmaxf(fmaxf(sc[0][i], sc[1][i]), fmaxf(sc[2][i], sc[3][i]));
            mx[i] = rowmax16_dpp(mx[i]);
        }

        // ---- defer-max (T13, log2 domain: threshold 11.5 bits ~ 8 nats) ----
        bool need = false;
#pragma unroll
        for (int i = 0; i < 4; ++i) need |= (mx[i] > m_run[i] + 11.5f);
        if (__any(need)) {
#pragma unroll
            for (int i = 0; i < 4; ++i) {
                float mnew = fmaxf(m_run[i], mx[i]);
                float scl = exp2_hw(m_run[i] - mnew);
                m_run[i] = mnew;
#pragma unroll
                for (int dt = 0; dt < 4; ++dt) acc[dt][i] *= scl;
                acc_l[i] *= scl;
            }
        }
#pragma unroll
        for (int i = 0; i < 4; ++i)
#pragma unroll
            for (int ht = 0; ht < 4; ++ht) sc[ht][i] = exp2_hw(sc[ht][i] - m_run[i]);

        // ---- P^T -> LDS (cvt_pk + 4x ds_write_b64), then P tr-reads ----
#pragma unroll
        for (int ht = 0; ht < 4; ++ht) {
            u32x2 pk;
            pk[0] = cvt_pk_bf16(sc[ht][0], sc[ht][1]);
            pk[1] = cvt_pk_bf16(sc[ht][2], sc[ht][3]);
            *reinterpret_cast<u32x2*>(pwr + ht * 512) = pk;
        }
        asm volatile("" ::: "memory");
        u32x2 pt_[4];
        TRR(pt_[0], va_p, 0);    TRR(pt_[1], va_p, 128);
        TRR(pt_[2], va_p, 1024); TRR(pt_[3], va_p, 1152);
        asm volatile("s_waitcnt lgkmcnt(0)" ::: "memory");
        __builtin_amdgcn_sched_barrier(0);

        union { u32x2 a[2]; bf16x8 v; } up0, up1;
        up0.a[0] = pt_[0]; up0.a[1] = pt_[1];
        up1.a[0] = pt_[2]; up1.a[1] = pt_[3];
        bf16x8 pa0 = up0.v, pa1 = up1.v;

        // ---- all MFMAs in one cluster ----
        __builtin_amdgcn_s_setprio(1);
        acc_l = __builtin_amdgcn_mfma_f32_16x16x32_bf16(pa0, ones, acc_l, 0, 0, 0);
        acc_l = __builtin_amdgcn_mfma_f32_16x16x32_bf16(pa1, ones, acc_l, 0, 0, 0);
#pragma unroll
        for (int dt = 0; dt < 4; ++dt) {
            union { u32x2 a[2]; bf16x8 v; } u0, u1;
            u0.a[0] = tv[dt][0]; u0.a[1] = tv[dt][1];
            u1.a[0] = tv[dt][2]; u1.a[1] = tv[dt][3];
            acc[dt] = __builtin_amdgcn_mfma_f32_16x16x32_bf16(pa0, u0.v, acc[dt], 0, 0, 0);
            acc[dt] = __builtin_amdgcn_mfma_f32_16x16x32_bf16(pa1, u1.v, acc[dt], 0, 0, 0);
        }
        __builtin_amdgcn_s_setprio(0);

        // prefetch had the whole tile to land; drain + sync
        asm volatile("s_waitcnt vmcnt(0)" ::: "memory");
        __syncthreads();
    }

    if (g == 0) {
        // single-chunk (qt<10): normalize and write attention output directly
        float rl[4];
#pragma unroll
        for (int i = 0; i < 4; ++i) rl[i] = 1.f / acc_l[i];
#pragma unroll
        for (int dt = 0; dt < 4; ++dt)
#pragma unroll
            for (int i = 0; i < 4; ++i) {
                int row = qrow0 + quad * 4 + i;
                size_t o = ((size_t)(b * SS) + row) * HIDN + h * HD + dt * 16 + cidx;
                a_out[o] = f2bf(acc[dt][i] * rl[i]);
            }
    } else {
        // multi-chunk: write unnormalized partials (m in log2 units)
#pragma unroll
        for (int dt = 0; dt < 4; ++dt)
#pragma unroll
            for (int i = 0; i < 4; ++i) {
                int row = w * 16 + quad * 4 + i;
                part_acc[((size_t)p * 64 + row) * 64 + dt * 16 + cidx] = f2bf(acc[dt][i]);
            }
        if (cidx == 0) {
#pragma unroll
            for (int i = 0; i < 4; ++i) {
                int row = w * 16 + quad * 4 + i;
                part_ml[((size_t)p * 64 + row) * 2 + 0] = m_run[i];
                part_ml[((size_t)p * 64 + row) * 2 + 1] = acc_l[i];
            }
        }
    }
}

// ---------- combine partials (rows s>=640, C in {2,3,4}) -> a_out ----------
__global__ __launch_bounds__(256) void k_combine(const unsigned short* __restrict__ part_acc,
                                                 const float* __restrict__ part_ml,
                                                 unsigned short* __restrict__ a_out) {
    int idx = blockIdx.x * 256 + threadIdx.x;  // BB*(SS-640)*NH*HD threads
    int d = idx & 63;
    int tmp = idx >> 6;
    int h = tmp % NH;
    int m2 = tmp / NH;               // [0, BB*(SS-640))
    int b = m2 / (SS - 640);
    int s = 640 + m2 % (SS - 640);
    int qt = s >> 6, row = s & 63;   // qt in [10,32)
    int g = (qt < 20) ? 1 : ((qt < 30) ? 2 : 3);
    int C = g + 1;
    int off = (g == 1) ? (10 + (qt - 10) * 2)
            : (g == 2) ? (30 + (qt - 20) * 3)
                       : (60 + (qt - 30) * 4);
    int pb = (b * NH + h) * NCHUNK + off;

    float2 ml[4];
    float M = -1e30f;
#pragma unroll
    for (int cc = 0; cc < 4; ++cc) {
        if (cc < C) {
            ml[cc] = *reinterpret_cast<const float2*>(&part_ml[((size_t)(pb + cc) * 64 + row) * 2]);
            M = fmaxf(M, ml[cc].x);
        } else {
            ml[cc] = make_float2(-1e30f, 0.f);
        }
    }
    float L = 0.f, O = 0.f;
#pragma unroll
    for (int cc = 0; cc < 4; ++cc) {
        if (cc < C) {
            float wgt = exp2_hw(ml[cc].x - M);
            L += ml[cc].y * wgt;
            O += bf2f(part_acc[((size_t)(pb + cc) * 64 + row) * 64 + d]) * wgt;
        }
    }
    a_out[((size_t)(b * SS) + s) * HIDN + h * 64 + d] = f2bf(O / L);
}

extern "C" void kernel_launch(void* const* d_in, const int* in_sizes, int n_in,
                              void* d_out, int out_size, void* d_ws, size_t ws_size,
                              hipStream_t stream) {
    (void)in_sizes; (void)n_in; (void)out_size; (void)ws_size;
    const float* h_f  = (const float*)d_in[0];
    const int*   pos  = (const int*)d_in[1];
    const float* Wq_f = (const float*)d_in[2];
    const float* Wk_f = (const float*)d_in[3];
    const float* Wv_f = (const float*)d_in[4];
    const float* Wo_f = (const float*)d_in[5];
    float* out = (float*)d_out;

    char* ws = (char*)d_ws;
    size_t off = 0;
    auto alloc = [&](size_t bytes) -> void* {
        void* p = ws + off;
        off += (bytes + 255) & ~(size_t)255;
        return p;
    };
    // region 0: h_bf (12.58MB, dead after QKV gemm) overlaid by part_acc (26.7MB)
    unsigned short* region0 = (unsigned short*)alloc((size_t)48 * NCHUNK * 64 * 64 * 2);
    unsigned short* h_bf     = region0;
    unsigned short* part_acc = region0;
    unsigned short* qkv_w  = (unsigned short*)alloc((size_t)NQKV * HIDN * 2);
    unsigned short* Wo_bf  = (unsigned short*)alloc((size_t)HIDN * NH * HD * 2);
    unsigned short* q_p    = (unsigned short*)alloc((size_t)MTOT * NH * HD * 2);
    unsigned short* k_p    = (unsigned short*)alloc((size_t)MTOT * NKV * HD * 2);
    unsigned short* v_p    = (unsigned short*)alloc((size_t)MTOT * NKV * HD * 2);
    unsigned short* a_out  = (unsigned short*)alloc((size_t)MTOT * HIDN * 2);
    float2* cs = (float2*)alloc((size_t)SS * 32 * 8);
    float* part_ml = (float*)alloc((size_t)BB * NH * NCHUNK * 64 * 2 * 4);

    // merged prep: hidden cast + weight casts + cos/sin table
    {
        int nH = MTOT * HIDN / 4;
        int nW = 2 * (HIDN * HIDN / 4) + 2 * (NKV * HD * HIDN / 4);
        int total = nH + nW + SS * 32;   // divisible by 256
        k_prep<<<total / 256, 256, 0, stream>>>(h_f, Wq_f, Wk_f, Wv_f, Wo_f,
                                                h_bf, qkv_w, Wo_bf, cs);
    }

    // fused QKV projection + RoPE + pack
    gemm_qkv<<<dim3(NQKV / 128, MTOT / 128), 256, 0, stream>>>(
        h_bf, qkv_w, pos, cs, q_p, k_p, v_p);

    // split-KV attention + combine (part_acc overlays the now-dead h_bf region)
    k_attn<<<dim3(NCHUNK, NH, BB), 256, 0, stream>>>(q_p, k_p, v_p, part_acc, part_ml, a_out);
    {
        int total = BB * (SS - 640) * NH * HD;   // 2*1408*24*64 = 4325376, /256 = 16896
        k_combine<<<total / 256, 256, 0, stream>>>(part_acc, part_ml, a_out);
    }

    // output projection
    gemm_bt<float><<<dim3(HIDN / 128, MTOT / 128), 256, 0, stream>>>(
        a_out, Wo_bf, out, HIDN, HIDN);
}

// Round 20
// 187.110 us; speedup vs baseline: 1.0069x; 1.0069x over previous
//
#include <hip/hip_runtime.h>
#include <hip/hip_bf16.h>

// ---- problem constants ----
#define HIDN 1536
#define NH   24
#define NKV  6
#define HD   64
#define BB   2
#define SS   2048
#define MTOT (BB*SS)   // 4096
#define NQKV 2304      // NH*HD + 2*NKV*HD
#define NCHUNK 60      // sum over qt=0..31 of ceil((qt+1)/12): 12 + 24 + 24
#define LOG2E 1.4426950408889634f

typedef __bf16 bf16x8 __attribute__((ext_vector_type(8)));
typedef float  f32x4  __attribute__((ext_vector_type(4)));
typedef unsigned short u16x8 __attribute__((ext_vector_type(8)));
typedef unsigned int   u32x2 __attribute__((ext_vector_type(2)));

typedef __attribute__((address_space(1))) const unsigned short as1_ushort;
typedef __attribute__((address_space(3))) unsigned short as3_ushort;

__device__ inline float bf2f(unsigned short u) {
    unsigned v = (unsigned)u << 16; float f; __builtin_memcpy(&f, &v, 4); return f;
}
__device__ inline unsigned short f2bf(float f) {
    unsigned u; __builtin_memcpy(&u, &f, 4);
    u = (u + 0x7FFFu + ((u >> 16) & 1u)) >> 16;
    return (unsigned short)u;
}
__device__ inline unsigned cvt_pk_bf16(float lo, float hi) {
    unsigned r;
    asm("v_cvt_pk_bf16_f32 %0, %1, %2" : "=v"(r) : "v"(lo), "v"(hi));
    return r;
}
// bare hardware 2^x (no libm fixup)
__device__ inline float exp2_hw(float x) {
    float r;
    asm("v_exp_f32 %0, %1" : "=v"(r) : "v"(x));
    return r;
}
// all-reduce max within each 16-lane DPP row via row_ror rotations (VALU-speed)
__device__ inline float rowmax16_dpp(float x) {
    int v, r;
    v = __float_as_int(x);
    r = __builtin_amdgcn_update_dpp(v, v, 0x121, 0xF, 0xF, false);  // row_ror:1
    x = fmaxf(x, __int_as_float(r));
    v = __float_as_int(x);
    r = __builtin_amdgcn_update_dpp(v, v, 0x122, 0xF, 0xF, false);  // row_ror:2
    x = fmaxf(x, __int_as_float(r));
    v = __float_as_int(x);
    r = __builtin_amdgcn_update_dpp(v, v, 0x124, 0xF, 0xF, false);  // row_ror:4
    x = fmaxf(x, __int_as_float(r));
    v = __float_as_int(x);
    r = __builtin_amdgcn_update_dpp(v, v, 0x128, 0xF, 0xF, false);  // row_ror:8
    x = fmaxf(x, __int_as_float(r));
    return x;
}

// XCD-chunked bijective block swizzle (requires nwg % 8 == 0):
// same-XCD blocks become consecutive in row-major order -> A/B panel L2 locality.
__device__ inline void xcd_swizzle(int& bx, int& by) {
    int gx = gridDim.x;
    int nwg = gx * gridDim.y;
    int flat = (int)blockIdx.y * gx + (int)blockIdx.x;
    int cpx = nwg >> 3;
    int swz = (flat & 7) * cpx + (flat >> 3);
    bx = swz % gx;
    by = swz / gx;
}

// ---------- merged prep: hidden cast + 4 weight casts + RoPE table ----------
__global__ __launch_bounds__(256) void k_prep(const float* __restrict__ h_f,
                                              const float* __restrict__ Wq,
                                              const float* __restrict__ Wk,
                                              const float* __restrict__ Wv,
                                              const float* __restrict__ Wo,
                                              unsigned short* __restrict__ h_bf,
                                              unsigned short* __restrict__ qkv_w,
                                              unsigned short* __restrict__ Wo_bf,
                                              float2* __restrict__ cs) {
    int i = blockIdx.x * 256 + threadIdx.x;
    const int nH = MTOT * HIDN / 4;        // 1572864
    const int nQ = HIDN * HIDN / 4;        // 589824
    const int nK = NKV * HD * HIDN / 4;    // 147456
    const int nW = 2 * nQ + 2 * nK;        // 1474560
    if (i < nH + nW) {
        const float* src; unsigned short* dst; int j;
        if (i < nH)                    { src = h_f; dst = h_bf;                        j = i; }
        else if ((i -= nH) < nQ)       { src = Wq;  dst = qkv_w;                       j = i; }
        else if (i < nQ + nK)          { src = Wk;  dst = qkv_w + (size_t)nQ * 4;      j = i - nQ; }
        else if (i < nQ + 2 * nK)      { src = Wv;  dst = qkv_w + (size_t)(nQ + nK) * 4; j = i - nQ - nK; }
        else                           { src = Wo;  dst = Wo_bf;                       j = i - nQ - 2 * nK; }
        float4 v = reinterpret_cast<const float4*>(src)[j];
        ushort4 o;
        o.x = f2bf(v.x); o.y = f2bf(v.y); o.z = f2bf(v.z); o.w = f2bf(v.w);
        reinterpret_cast<ushort4*>(dst)[j] = o;
        return;
    }
    int k = i - (nH + nW);
    if (k < SS * 32) {
        int s = k >> 5, f = k & 31;
        double inv = pow(10000.0, -(double)f / 32.0);
        double ang = (double)s * inv;
        cs[k] = make_float2((float)cos(ang), (float)sin(ang));
    }
}

// ---------- GEMM, BK=64, XOR-swizzled LDS, double-buffered, XCD-swizzled grid ----------
template <typename OutT>
__global__ __launch_bounds__(256) void gemm_bt(const unsigned short* __restrict__ A,
                                               const unsigned short* __restrict__ Bt,
                                               OutT* __restrict__ C,
                                               int N, int K) {
    __shared__ unsigned short Alds[2][128 * 64];   // 2 x 16KB
    __shared__ unsigned short Blds[2][128 * 64];   // 2 x 16KB
    int t = threadIdx.x;
    int lane = t & 63, w = t >> 6;
    int bx, by;
    xcd_swizzle(bx, by);
    int m0 = by * 128, n0 = bx * 128;
    int wm = (w >> 1) * 64, wn = (w & 1) * 64;
    int cidx = lane & 15, quad = lane >> 4;
    int srow = lane >> 3, scol = (lane & 7) * 8;

    int srcoff[4], dstoff[4];
#pragma unroll
    for (int c = 0; c < 4; ++c) {
        int chunk = w + c * 4;
        int row = chunk * 8 + srow;
        int col = scol ^ ((row & 7) * 8);
        srcoff[c] = row * K + col;
        dstoff[c] = chunk * 512;
    }

    f32x4 zero = {0.f, 0.f, 0.f, 0.f};
    f32x4 acc[4][4];
#pragma unroll
    for (int mi = 0; mi < 4; ++mi)
#pragma unroll
        for (int ni = 0; ni < 4; ++ni) acc[mi][ni] = zero;

    const unsigned short* Ab = A + (size_t)m0 * K;
    const unsigned short* Bb = Bt + (size_t)n0 * K;

#pragma unroll
    for (int c = 0; c < 4; ++c) {
        __builtin_amdgcn_global_load_lds((as1_ushort*)(Ab + srcoff[c]),
                                         (as3_ushort*)&Alds[0][dstoff[c]], 16, 0, 0);
        __builtin_amdgcn_global_load_lds((as1_ushort*)(Bb + srcoff[c]),
                                         (as3_ushort*)&Blds[0][dstoff[c]], 16, 0, 0);
    }
    asm volatile("s_waitcnt vmcnt(0)" ::: "memory");
    __syncthreads();

    int nk = K >> 6;
    for (int kt = 0; kt < nk; ++kt) {
        int cur = kt & 1;
        if (kt + 1 < nk) {
            int koff = (kt + 1) * 64;
#pragma unroll
            for (int c = 0; c < 4; ++c) {
                __builtin_amdgcn_global_load_lds((as1_ushort*)(Ab + srcoff[c] + koff),
                                                 (as3_ushort*)&Alds[cur ^ 1][dstoff[c]], 16, 0, 0);
                __builtin_amdgcn_global_load_lds((as1_ushort*)(Bb + srcoff[c] + koff),
                                                 (as3_ushort*)&Blds[cur ^ 1][dstoff[c]], 16, 0, 0);
            }
        }
#pragma unroll
        for (int ka = 0; ka < 2; ++ka) {
            bf16x8 af[4], bfr[4];
#pragma unroll
            for (int mi = 0; mi < 4; ++mi) {
                int arow = wm + mi * 16 + cidx;
                af[mi] = *reinterpret_cast<bf16x8*>(
                    &Alds[cur][arow * 64 + ((ka * 32 + quad * 8) ^ ((arow & 7) * 8))]);
            }
#pragma unroll
            for (int ni = 0; ni < 4; ++ni) {
                int brow = wn + ni * 16 + cidx;
                bfr[ni] = *reinterpret_cast<bf16x8*>(
                    &Blds[cur][brow * 64 + ((ka * 32 + quad * 8) ^ ((brow & 7) * 8))]);
            }
#pragma unroll
            for (int mi = 0; mi < 4; ++mi)
#pragma unroll
                for (int ni = 0; ni < 4; ++ni)
                    acc[mi][ni] = __builtin_amdgcn_mfma_f32_16x16x32_bf16(af[mi], bfr[ni],
                                                                          acc[mi][ni], 0, 0, 0);
        }
        asm volatile("s_waitcnt vmcnt(0)" ::: "memory");
        __syncthreads();
    }
#pragma unroll
    for (int mi = 0; mi < 4; ++mi)
#pragma unroll
        for (int ni = 0; ni < 4; ++ni)
#pragma unroll
            for (int i = 0; i < 4; ++i) {
                int row = m0 + wm + mi * 16 + quad * 4 + i;
                int col = n0 + wn + ni * 16 + cidx;
                C[(size_t)row * N + col] = acc[mi][ni][i];
            }
}

// ---------- fused QKV GEMM (BK=64, swizzled, double-buffered, XCD-swizzled) ----------
__global__ __launch_bounds__(256) void gemm_qkv(const unsigned short* __restrict__ A,
                                                const unsigned short* __restrict__ Bt,
                                                const int* __restrict__ pos_ids,
                                                const float2* __restrict__ cs,
                                                unsigned short* __restrict__ q_p,
                                                unsigned short* __restrict__ k_p,
                                                unsigned short* __restrict__ v_p) {
    __shared__ unsigned short Alds[2][128 * 64];
    __shared__ unsigned short Blds[2][128 * 64];
    int t = threadIdx.x;
    int lane = t & 63, w = t >> 6;
    int bx, by;
    xcd_swizzle(bx, by);
    int m0 = by * 128, n0 = bx * 128;
    int wm = (w >> 1) * 64, wn = (w & 1) * 64;
    int cidx = lane & 15, quad = lane >> 4;
    int srow = lane >> 3, scol = (lane & 7) * 8;

    int srcoff[4], dstoff[4];
#pragma unroll
    for (int c = 0; c < 4; ++c) {
        int chunk = w + c * 4;
        int row = chunk * 8 + srow;
        int col = scol ^ ((row & 7) * 8);
        srcoff[c] = row * HIDN + col;
        dstoff[c] = chunk * 512;
    }

    f32x4 zero = {0.f, 0.f, 0.f, 0.f};
    f32x4 acc[4][4];
#pragma unroll
    for (int mi = 0; mi < 4; ++mi)
#pragma unroll
        for (int ni = 0; ni < 4; ++ni) acc[mi][ni] = zero;

    const unsigned short* Ab = A + (size_t)m0 * HIDN;
    const unsigned short* Bb = Bt + (size_t)n0 * HIDN;

#pragma unroll
    for (int c = 0; c < 4; ++c) {
        __builtin_amdgcn_global_load_lds((as1_ushort*)(Ab + srcoff[c]),
                                         (as3_ushort*)&Alds[0][dstoff[c]], 16, 0, 0);
        __builtin_amdgcn_global_load_lds((as1_ushort*)(Bb + srcoff[c]),
                                         (as3_ushort*)&Blds[0][dstoff[c]], 16, 0, 0);
    }
    asm volatile("s_waitcnt vmcnt(0)" ::: "memory");
    __syncthreads();

    const int nk = HIDN >> 6;
    for (int kt = 0; kt < nk; ++kt) {
        int cur = kt & 1;
        if (kt + 1 < nk) {
            int koff = (kt + 1) * 64;
#pragma unroll
            for (int c = 0; c < 4; ++c) {
                __builtin_amdgcn_global_load_lds((as1_ushort*)(Ab + srcoff[c] + koff),
                                                 (as3_ushort*)&Alds[cur ^ 1][dstoff[c]], 16, 0, 0);
                __builtin_amdgcn_global_load_lds((as1_ushort*)(Bb + srcoff[c] + koff),
                                                 (as3_ushort*)&Blds[cur ^ 1][dstoff[c]], 16, 0, 0);
            }
        }
#pragma unroll
        for (int ka = 0; ka < 2; ++ka) {
            bf16x8 af[4], bfr[4];
#pragma unroll
            for (int mi = 0; mi < 4; ++mi) {
                int arow = wm + mi * 16 + cidx;
                af[mi] = *reinterpret_cast<bf16x8*>(
                    &Alds[cur][arow * 64 + ((ka * 32 + quad * 8) ^ ((arow & 7) * 8))]);
            }
#pragma unroll
            for (int ni = 0; ni < 4; ++ni) {
                int brow = wn + ni * 16 + cidx;
                bfr[ni] = *reinterpret_cast<bf16x8*>(
                    &Blds[cur][brow * 64 + ((ka * 32 + quad * 8) ^ ((brow & 7) * 8))]);
            }
#pragma unroll
            for (int mi = 0; mi < 4; ++mi)
#pragma unroll
                for (int ni = 0; ni < 4; ++ni)
                    acc[mi][ni] = __builtin_amdgcn_mfma_f32_16x16x32_bf16(af[mi], bfr[ni],
                                                                          acc[mi][ni], 0, 0, 0);
        }
        asm volatile("s_waitcnt vmcnt(0)" ::: "memory");
        __syncthreads();
    }

    // ---- fused epilogue ----
    int colbase = n0 + wn;   // multiple of 64 -> exactly one head
    if (colbase >= NH * HD + NKV * HD) {        // V segment: plain pack
        int h = (colbase - (NH * HD + NKV * HD)) >> 6;
#pragma unroll
        for (int mi = 0; mi < 4; ++mi)
#pragma unroll
            for (int i = 0; i < 4; ++i) {
                int row = m0 + wm + mi * 16 + quad * 4 + i;
                int b = row >> 11, s = row & 2047;
                size_t base = ((size_t)(b * NKV + h) * SS + s) * 64;
#pragma unroll
                for (int ni = 0; ni < 4; ++ni)
                    v_p[base + ni * 16 + cidx] = f2bf(acc[mi][ni][i]);
            }
    } else {
        bool isQ = colbase < NH * HD;
        unsigned short* dst = isQ ? q_p : k_p;
        int h = isQ ? (colbase >> 6) : ((colbase - NH * HD) >> 6);
        int H = isQ ? NH : NKV;
        float scl = isQ ? (0.125f * LOG2E) : 1.0f;  // Q pre-scaled; log2-domain softmax
#pragma unroll
        for (int mi = 0; mi < 4; ++mi)
#pragma unroll
            for (int i = 0; i < 4; ++i) {
                int row = m0 + wm + mi * 16 + quad * 4 + i;
                int b = row >> 11, s = row & 2047;
                int pos = pos_ids[row];
                float2 c1 = cs[pos * 32 + cidx];
                float2 c2 = cs[pos * 32 + 16 + cidx];
                size_t base = ((size_t)(b * H + h) * SS + s) * 64;
                float x10 = acc[mi][0][i], x20 = acc[mi][2][i];
                float x11 = acc[mi][1][i], x21 = acc[mi][3][i];
                dst[base + cidx]       = f2bf((x10 * c1.x - x20 * c1.y) * scl);
                dst[base + 32 + cidx]  = f2bf((x20 * c1.x + x10 * c1.y) * scl);
                dst[base + 16 + cidx]  = f2bf((x11 * c2.x - x21 * c2.y) * scl);
                dst[base + 48 + cidx]  = f2bf((x21 * c2.x + x11 * c2.y) * scl);
            }
    }
}

// ---------- split-KV flash attention: chunks of <=12 tiles, balanced split ----------
// C(qt)=ceil((qt+1)/12) in {1,2,3}; NCHUNK=60. qt<12: single chunk, direct write.
// Chunk c covers tiles [c*ntot/C, (c+1)*ntot/C).
#define TRR(dst, ADDR, OFF) asm volatile("ds_read_b64_tr_b16 %0, %1 offset:" #OFF \
                                         : "=v"(dst) : "v"(ADDR))

__global__ __launch_bounds__(256, 4) void k_attn(const unsigned short* __restrict__ Qp,
                                                 const unsigned short* __restrict__ Kp,
                                                 const unsigned short* __restrict__ Vp,
                                                 unsigned short* __restrict__ part_acc,
                                                 float* __restrict__ part_ml,
                                                 unsigned short* __restrict__ a_out) {
    int bxr = NCHUNK - 1 - (int)blockIdx.x;   // heavy (large qt) first
    int h = blockIdx.y, b = blockIdx.z;
    int kvh = h >> 2;
    // decode bxr -> (g, qt, c): g0 = qt 0..11 (12), g1 = qt 12..23 x2 (24), g2 = qt 24..31 x3 (24)
    int g, qt, c;
    if (bxr < 12)      { g = 0; qt = bxr; c = 0; }
    else if (bxr < 36) { g = 1; int idx = bxr - 12; qt = 12 + (idx >> 1); c = idx & 1; }
    else               { g = 2; int idx = bxr - 36; qt = 24 + idx / 3; c = idx % 3; }
    int p = (b * NH + h) * NCHUNK + bxr;
    int qbase = qt * 64;
    int ntot = qt + 1, C = g + 1;
    int t0 = c * ntot / C;
    int nt = (c + 1) * ntot / C - t0;
    int ck0 = t0 * 64;

    int t = threadIdx.x, lane = t & 63, w = t >> 6;
    int cidx = lane & 15, quad = lane >> 4;
    int qrow0 = qbase + w * 16;

    const unsigned short* qptr  = Qp + ((size_t)(b * NH + h) * SS + qrow0) * HD;
    const unsigned short* kbase = Kp + (((size_t)(b * NKV + kvh) * SS) + ck0) * HD;
    const unsigned short* vbase = Vp + (((size_t)(b * NKV + kvh) * SS) + ck0) * HD;

    __shared__ unsigned short Klds[2 * 4096];    // 2 x 8KB tiled K [ht][ka][quad][cidx][8]
    __shared__ unsigned short Vt[2 * 4096];      // 2 x 8KB tiled V [d16][kv4][4][16]
    __shared__ unsigned short Pt[4][64 * 16];    // per-wave P^T

    const unsigned short* ksrc[2];
    const unsigned short* vsrc[2];
#pragma unroll
    for (int i = 0; i < 2; ++i) {
        int o = (w * 2 + i) * 512 + lane * 8;
        int kh = o >> 10, ka_ = (o >> 9) & 1, kq = (o >> 7) & 3, kc = (o >> 3) & 15;
        ksrc[i] = kbase + (kh * 16 + kc) * HD + ka_ * 32 + kq * 8;
        int r = o & 1023;
        int kv = ((r >> 6) << 2) | ((r >> 4) & 3);
        int d  = ((o >> 10) << 4) | (r & 15);
        vsrc[i] = vbase + kv * HD + d;
    }

    bf16x8 qa[2];
#pragma unroll
    for (int ka = 0; ka < 2; ++ka)
        qa[ka] = *reinterpret_cast<const bf16x8*>(qptr + (size_t)cidx * HD + ka * 32 + quad * 8);

    bf16x8 ones;
    {
        unsigned short ob = 0x3F80;  // bf16 1.0
        u16x8 ov;
#pragma unroll
        for (int j = 0; j < 8; ++j) ov[j] = ob;
        __builtin_memcpy(&ones, &ov, 16);
    }

    f32x4 zero = {0.f, 0.f, 0.f, 0.f};
    f32x4 acc[4], acc_l = zero;
    float m_run[4];
#pragma unroll
    for (int i = 0; i < 4; ++i) { acc[i] = zero; m_run[i] = -1e30f; }

    // prologue: stage K0,V0 into buf 0
#pragma unroll
    for (int i = 0; i < 2; ++i) {
        __builtin_amdgcn_global_load_lds((as1_ushort*)ksrc[i],
                                         (as3_ushort*)&Klds[(w * 2 + i) * 512], 16, 0, 0);
        __builtin_amdgcn_global_load_lds((as1_ushort*)vsrc[i],
                                         (as3_ushort*)&Vt[(w * 2 + i) * 512], 16, 0, 0);
    }
    asm volatile("s_waitcnt vmcnt(0)" ::: "memory");
    __syncthreads();

    unsigned vtb  = (unsigned)(uintptr_t)(as3_ushort*)&Vt[0];
    unsigned va_base = vtb + (unsigned)(quad * 256 + cidx * 8);
    unsigned ptb  = (unsigned)(uintptr_t)(as3_ushort*)&Pt[w][0];
    unsigned va_p = ptb + (unsigned)(quad * 256 + cidx * 8);
    char* pwr = (char*)&Pt[w][0] + cidx * 32 + quad * 8;

    for (int it = 0; it < nt; ++it) {
        int cur = it & 1;
        int kvb = ck0 + it * 64;

        // ---- issue next-tile K+V prefetch ----
        if (it + 1 < nt) {
            size_t nv = (size_t)(it + 1) * 64 * HD;
#pragma unroll
            for (int i = 0; i < 2; ++i) {
                __builtin_amdgcn_global_load_lds(
                    (as1_ushort*)(ksrc[i] + nv),
                    (as3_ushort*)&Klds[(cur ^ 1) * 4096 + (w * 2 + i) * 512], 16, 0, 0);
                __builtin_amdgcn_global_load_lds(
                    (as1_ushort*)(vsrc[i] + nv),
                    (as3_ushort*)&Vt[(cur ^ 1) * 4096 + (w * 2 + i) * 512], 16, 0, 0);
            }
        }

        // ---- QK^T from LDS ----
        bf16x8 kb[4][2];
#pragma unroll
        for (int ht = 0; ht < 4; ++ht)
#pragma unroll
            for (int ka = 0; ka < 2; ++ka)
                kb[ht][ka] = *reinterpret_cast<bf16x8*>(
                    &Klds[cur * 4096 + ht * 1024 + ka * 512 + quad * 128 + cidx * 8]);
        f32x4 sc[4];
#pragma unroll
        for (int ht = 0; ht < 4; ++ht) {
            f32x4 cacc = zero;
            cacc = __builtin_amdgcn_mfma_f32_16x16x32_bf16(qa[0], kb[ht][0], cacc, 0, 0, 0);
            cacc = __builtin_amdgcn_mfma_f32_16x16x32_bf16(qa[1], kb[ht][1], cacc, 0, 0, 0);
            sc[ht] = cacc;
        }

        // ---- V tr-reads hoisted (V[cur] drained last iter; latency hides under softmax) ----
        unsigned va = va_base + (unsigned)(cur * 8192);
        u32x2 tv[4][4];
        TRR(tv[0][0], va, 0);    TRR(tv[0][1], va, 128);
        TRR(tv[0][2], va, 1024); TRR(tv[0][3], va, 1152);
        TRR(tv[1][0], va, 2048); TRR(tv[1][1], va, 2176);
        TRR(tv[1][2], va, 3072); TRR(tv[1][3], va, 3200);
        TRR(tv[2][0], va, 4096); TRR(tv[2][1], va, 4224);
        TRR(tv[2][2], va, 5120); TRR(tv[2][3], va, 5248);
        TRR(tv[3][0], va, 6144); TRR(tv[3][1], va, 6272);
        TRR(tv[3][2], va, 7168); TRR(tv[3][3], va, 7296);

        // ---- causal mask (diagonal tile only) ----
        if (kvb + 63 > qrow0) {
#pragma unroll
            for (int ht = 0; ht < 4; ++ht)
#pragma unroll
                for (int i = 0; i < 4; ++i)
                    if (kvb + ht * 16 + cidx > qrow0 + quad * 4 + i) sc[ht][i] = -1e30f;
        }

        // ---- row max via DPP rotations ----
        float mx[4];
#pragma unroll
        for (int i = 0; i < 4; ++i) {
            mx[i] = fmaxf(fmaxf(sc[0][i], sc[1][i]), fmaxf(sc[2][i], sc[3][i]));
            mx[i] = rowmax16_dpp(mx[i]);
        }

        // ---- defer-max (T13, log2 domain: threshold 11.5 bits ~ 8 nats) ----
        bool need = false;
#pragma unroll
        for (int i = 0; i < 4; ++i) need |= (mx[i] > m_run[i] + 11.5f);
        if (__any(need)) {
#pragma unroll
            for (int i = 0; i < 4; ++i) {
                float mnew = fmaxf(m_run[i], mx[i]);
                float scl = exp2_hw(m_run[i] - mnew);
                m_run[i] = mnew;
#pragma unroll
                for (int dt = 0; dt < 4; ++dt) acc[dt][i] *= scl;
                acc_l[i] *= scl;
            }
        }
#pragma unroll
        for (int i = 0; i < 4; ++i)
#pragma unroll
            for (int ht = 0; ht < 4; ++ht) sc[ht][i] = exp2_hw(sc[ht][i] - m_run[i]);

        // ---- P^T -> LDS (cvt_pk + 4x ds_write_b64), then P tr-reads ----
#pragma unroll
        for (int ht = 0; ht < 4; ++ht) {
            u32x2 pk;
            pk[0] = cvt_pk_bf16(sc[ht][0], sc[ht][1]);
            pk[1] = cvt_pk_bf16(sc[ht][2], sc[ht][3]);
            *reinterpret_cast<u32x2*>(pwr + ht * 512) = pk;
        }
        asm volatile("" ::: "memory");
        u32x2 pt_[4];
        TRR(pt_[0], va_p, 0);    TRR(pt_[1], va_p, 128);
        TRR(pt_[2], va_p, 1024); TRR(pt_[3], va_p, 1152);
        asm volatile("s_waitcnt lgkmcnt(0)" ::: "memory");
        __builtin_amdgcn_sched_barrier(0);

        union { u32x2 a[2]; bf16x8 v; } up0, up1;
        up0.a[0] = pt_[0]; up0.a[1] = pt_[1];
        up1.a[0] = pt_[2]; up1.a[1] = pt_[3];
        bf16x8 pa0 = up0.v, pa1 = up1.v;

        // ---- all MFMAs in one cluster ----
        __builtin_amdgcn_s_setprio(1);
        acc_l = __builtin_amdgcn_mfma_f32_16x16x32_bf16(pa0, ones, acc_l, 0, 0, 0);
        acc_l = __builtin_amdgcn_mfma_f32_16x16x32_bf16(pa1, ones, acc_l, 0, 0, 0);
#pragma unroll
        for (int dt = 0; dt < 4; ++dt) {
            union { u32x2 a[2]; bf16x8 v; } u0, u1;
            u0.a[0] = tv[dt][0]; u0.a[1] = tv[dt][1];
            u1.a[0] = tv[dt][2]; u1.a[1] = tv[dt][3];
            acc[dt] = __builtin_amdgcn_mfma_f32_16x16x32_bf16(pa0, u0.v, acc[dt], 0, 0, 0);
            acc[dt] = __builtin_amdgcn_mfma_f32_16x16x32_bf16(pa1, u1.v, acc[dt], 0, 0, 0);
        }
        __builtin_amdgcn_s_setprio(0);

        // prefetch had the whole tile to land; drain + sync
        asm volatile("s_waitcnt vmcnt(0)" ::: "memory");
        __syncthreads();
    }

    if (g == 0) {
        // single-chunk (qt<12): normalize and write attention output directly
        float rl[4];
#pragma unroll
        for (int i = 0; i < 4; ++i) rl[i] = 1.f / acc_l[i];
#pragma unroll
        for (int dt = 0; dt < 4; ++dt)
#pragma unroll
            for (int i = 0; i < 4; ++i) {
                int row = qrow0 + quad * 4 + i;
                size_t o = ((size_t)(b * SS) + row) * HIDN + h * HD + dt * 16 + cidx;
                a_out[o] = f2bf(acc[dt][i] * rl[i]);
            }
    } else {
        // multi-chunk: write unnormalized partials (m in log2 units)
#pragma unroll
        for (int dt = 0; dt < 4; ++dt)
#pragma unroll
            for (int i = 0; i < 4; ++i) {
                int row = w * 16 + quad * 4 + i;
                part_acc[((size_t)p * 64 + row) * 64 + dt * 16 + cidx] = f2bf(acc[dt][i]);
            }
        if (cidx == 0) {
#pragma unroll
            for (int i = 0; i < 4; ++i) {
                int row = w * 16 + quad * 4 + i;
                part_ml[((size_t)p * 64 + row) * 2 + 0] = m_run[i];
                part_ml[((size_t)p * 64 + row) * 2 + 1] = acc_l[i];
            }
        }
    }
}

// ---------- combine partials (rows s>=768 only, C in {2,3}) -> a_out ----------
__global__ __launch_bounds__(256) void k_combine(const unsigned short* __restrict__ part_acc,
                                                 const float* __restrict__ part_ml,
                                                 unsigned short* __restrict__ a_out) {
    int idx = blockIdx.x * 256 + threadIdx.x;  // BB*(SS-768)*NH*HD threads
    int d = idx & 63;
    int tmp = idx >> 6;
    int h = tmp % NH;
    int m2 = tmp / NH;               // [0, BB*(SS-768))
    int b = m2 / (SS - 768);
    int s = 768 + m2 % (SS - 768);
    int qt = s >> 6, row = s & 63;   // qt in [12,32)
    int g = (qt < 24) ? 1 : 2;
    int C = g + 1;
    int off = (g == 1) ? (12 + (qt - 12) * 2) : (36 + (qt - 24) * 3);
    int pb = (b * NH + h) * NCHUNK + off;

    float2 ml[3];
    float M = -1e30f;
#pragma unroll
    for (int cc = 0; cc < 3; ++cc) {
        if (cc < C) {
            ml[cc] = *reinterpret_cast<const float2*>(&part_ml[((size_t)(pb + cc) * 64 + row) * 2]);
            M = fmaxf(M, ml[cc].x);
        } else {
            ml[cc] = make_float2(-1e30f, 0.f);
        }
    }
    float L = 0.f, O = 0.f;
#pragma unroll
    for (int cc = 0; cc < 3; ++cc) {
        if (cc < C) {
            float wgt = exp2_hw(ml[cc].x - M);
            L += ml[cc].y * wgt;
            O += bf2f(part_acc[((size_t)(pb + cc) * 64 + row) * 64 + d]) * wgt;
        }
    }
    a_out[((size_t)(b * SS) + s) * HIDN + h * 64 + d] = f2bf(O / L);
}

extern "C" void kernel_launch(void* const* d_in, const int* in_sizes, int n_in,
                              void* d_out, int out_size, void* d_ws, size_t ws_size,
                              hipStream_t stream) {
    (void)in_sizes; (void)n_in; (void)out_size; (void)ws_size;
    const float* h_f  = (const float*)d_in[0];
    const int*   pos  = (const int*)d_in[1];
    const float* Wq_f = (const float*)d_in[2];
    const float* Wk_f = (const float*)d_in[3];
    const float* Wv_f = (const float*)d_in[4];
    const float* Wo_f = (const float*)d_in[5];
    float* out = (float*)d_out;

    char* ws = (char*)d_ws;
    size_t off = 0;
    auto alloc = [&](size_t bytes) -> void* {
        void* p = ws + off;
        off += (bytes + 255) & ~(size_t)255;
        return p;
    };
    // region 0: h_bf (12.58MB, dead after QKV gemm) overlaid by part_acc (23.6MB)
    unsigned short* region0 = (unsigned short*)alloc((size_t)48 * NCHUNK * 64 * 64 * 2);
    unsigned short* h_bf     = region0;
    unsigned short* part_acc = region0;
    unsigned short* qkv_w  = (unsigned short*)alloc((size_t)NQKV * HIDN * 2);
    unsigned short* Wo_bf  = (unsigned short*)alloc((size_t)HIDN * NH * HD * 2);
    unsigned short* q_p    = (unsigned short*)alloc((size_t)MTOT * NH * HD * 2);
    unsigned short* k_p    = (unsigned short*)alloc((size_t)MTOT * NKV * HD * 2);
    unsigned short* v_p    = (unsigned short*)alloc((size_t)MTOT * NKV * HD * 2);
    unsigned short* a_out  = (unsigned short*)alloc((size_t)MTOT * HIDN * 2);
    float2* cs = (float2*)alloc((size_t)SS * 32 * 8);
    float* part_ml = (float*)alloc((size_t)BB * NH * NCHUNK * 64 * 2 * 4);

    // merged prep: hidden cast + weight casts + cos/sin table
    {
        int nH = MTOT * HIDN / 4;
        int nW = 2 * (HIDN * HIDN / 4) + 2 * (NKV * HD * HIDN / 4);
        int total = nH + nW + SS * 32;   // divisible by 256
        k_prep<<<total / 256, 256, 0, stream>>>(h_f, Wq_f, Wk_f, Wv_f, Wo_f,
                                                h_bf, qkv_w, Wo_bf, cs);
    }

    // fused QKV projection + RoPE + pack
    gemm_qkv<<<dim3(NQKV / 128, MTOT / 128), 256, 0, stream>>>(
        h_bf, qkv_w, pos, cs, q_p, k_p, v_p);

    // split-KV attention + combine (part_acc overlays the now-dead h_bf region)
    k_attn<<<dim3(NCHUNK, NH, BB), 256, 0, stream>>>(q_p, k_p, v_p, part_acc, part_ml, a_out);
    {
        int total = BB * (SS - 768) * NH * HD;   // 2*1280*24*64 = 3932160, /256 = 15360
        k_combine<<<total / 256, 256, 0, stream>>>(part_acc, part_ml, a_out);
    }

    // output projection
    gemm_bt<float><<<dim3(HIDN / 128, MTOT / 128), 256, 0, stream>>>(
        a_out, Wo_bf, out, HIDN, HIDN);
}

// Round 21
// 184.804 us; speedup vs baseline: 1.0194x; 1.0125x over previous
//
#include <hip/hip_runtime.h>
#include <hip/hip_bf16.h>

// ---- problem constants ----
#define HIDN 1536
#define NH   24
#define NKV  6
#define HD   64
#define BB   2
#define SS   2048
#define MTOT (BB*SS)   // 4096
#define NQKV 2304      // NH*HD + 2*NKV*HD
#define NCHUNK 60      // sum over qt=0..31 of ceil((qt+1)/12): 12 + 24 + 24
#define LOG2E 1.4426950408889634f

typedef __bf16 bf16x8 __attribute__((ext_vector_type(8)));
typedef float  f32x4  __attribute__((ext_vector_type(4)));
typedef unsigned short u16x8 __attribute__((ext_vector_type(8)));
typedef unsigned int   u32x2 __attribute__((ext_vector_type(2)));

typedef __attribute__((address_space(1))) const unsigned short as1_ushort;
typedef __attribute__((address_space(3))) unsigned short as3_ushort;

__device__ inline float bf2f(unsigned short u) {
    unsigned v = (unsigned)u << 16; float f; __builtin_memcpy(&f, &v, 4); return f;
}
__device__ inline unsigned short f2bf(float f) {
    unsigned u; __builtin_memcpy(&u, &f, 4);
    u = (u + 0x7FFFu + ((u >> 16) & 1u)) >> 16;
    return (unsigned short)u;
}
__device__ inline unsigned cvt_pk_bf16(float lo, float hi) {
    unsigned r;
    asm("v_cvt_pk_bf16_f32 %0, %1, %2" : "=v"(r) : "v"(lo), "v"(hi));
    return r;
}
// bare hardware 2^x (no libm fixup)
__device__ inline float exp2_hw(float x) {
    float r;
    asm("v_exp_f32 %0, %1" : "=v"(r) : "v"(x));
    return r;
}
// all-reduce max within each 16-lane DPP row via row_ror rotations (VALU-speed)
__device__ inline float rowmax16_dpp(float x) {
    int v, r;
    v = __float_as_int(x);
    r = __builtin_amdgcn_update_dpp(v, v, 0x121, 0xF, 0xF, false);  // row_ror:1
    x = fmaxf(x, __int_as_float(r));
    v = __float_as_int(x);
    r = __builtin_amdgcn_update_dpp(v, v, 0x122, 0xF, 0xF, false);  // row_ror:2
    x = fmaxf(x, __int_as_float(r));
    v = __float_as_int(x);
    r = __builtin_amdgcn_update_dpp(v, v, 0x124, 0xF, 0xF, false);  // row_ror:4
    x = fmaxf(x, __int_as_float(r));
    v = __float_as_int(x);
    r = __builtin_amdgcn_update_dpp(v, v, 0x128, 0xF, 0xF, false);  // row_ror:8
    x = fmaxf(x, __int_as_float(r));
    return x;
}

// XCD-chunked bijective block swizzle (requires nwg % 8 == 0):
// same-XCD blocks become consecutive in row-major order -> A/B panel L2 locality.
__device__ inline void xcd_swizzle(int& bx, int& by) {
    int gx = gridDim.x;
    int nwg = gx * gridDim.y;
    int flat = (int)blockIdx.y * gx + (int)blockIdx.x;
    int cpx = nwg >> 3;
    int swz = (flat & 7) * cpx + (flat >> 3);
    bx = swz % gx;
    by = swz / gx;
}

// ---------- merged prep: hidden cast + 4 weight casts + RoPE table (f32 trig) ----------
__global__ __launch_bounds__(256) void k_prep(const float* __restrict__ h_f,
                                              const float* __restrict__ Wq,
                                              const float* __restrict__ Wk,
                                              const float* __restrict__ Wv,
                                              const float* __restrict__ Wo,
                                              unsigned short* __restrict__ h_bf,
                                              unsigned short* __restrict__ qkv_w,
                                              unsigned short* __restrict__ Wo_bf,
                                              float2* __restrict__ cs) {
    int i = blockIdx.x * 256 + threadIdx.x;
    const int nH = MTOT * HIDN / 4;        // 1572864
    const int nQ = HIDN * HIDN / 4;        // 589824
    const int nK = NKV * HD * HIDN / 4;    // 147456
    const int nW = 2 * nQ + 2 * nK;        // 1474560
    if (i < nH + nW) {
        const float* src; unsigned short* dst; int j;
        if (i < nH)                    { src = h_f; dst = h_bf;                        j = i; }
        else if ((i -= nH) < nQ)       { src = Wq;  dst = qkv_w;                       j = i; }
        else if (i < nQ + nK)          { src = Wk;  dst = qkv_w + (size_t)nQ * 4;      j = i - nQ; }
        else if (i < nQ + 2 * nK)      { src = Wv;  dst = qkv_w + (size_t)(nQ + nK) * 4; j = i - nQ - nK; }
        else                           { src = Wo;  dst = Wo_bf;                       j = i - nQ - 2 * nK; }
        float4 v = reinterpret_cast<const float4*>(src)[j];
        ushort4 o;
        o.x = f2bf(v.x); o.y = f2bf(v.y); o.z = f2bf(v.z); o.w = f2bf(v.w);
        reinterpret_cast<ushort4*>(dst)[j] = o;
        return;
    }
    int k = i - (nH + nW);
    if (k < SS * 32) {
        int s = k >> 5, f = k & 31;
        // inv = 10000^(-f/32) via hw exp2; log2(10000)/32 = 0.41524101186092494
        float inv = exp2_hw(-(float)f * 0.41524101186092494f);
        float ang = (float)s * inv;
        cs[k] = make_float2(cosf(ang), sinf(ang));
    }
}

// ---------- GEMM, BK=64, XOR-swizzled LDS, double-buffered, XCD-swizzled grid ----------
template <typename OutT>
__global__ __launch_bounds__(256) void gemm_bt(const unsigned short* __restrict__ A,
                                               const unsigned short* __restrict__ Bt,
                                               OutT* __restrict__ C,
                                               int N, int K) {
    __shared__ unsigned short Alds[2][128 * 64];   // 2 x 16KB
    __shared__ unsigned short Blds[2][128 * 64];   // 2 x 16KB
    int t = threadIdx.x;
    int lane = t & 63, w = t >> 6;
    int bx, by;
    xcd_swizzle(bx, by);
    int m0 = by * 128, n0 = bx * 128;
    int wm = (w >> 1) * 64, wn = (w & 1) * 64;
    int cidx = lane & 15, quad = lane >> 4;
    int srow = lane >> 3, scol = (lane & 7) * 8;

    int srcoff[4], dstoff[4];
#pragma unroll
    for (int c = 0; c < 4; ++c) {
        int chunk = w + c * 4;
        int row = chunk * 8 + srow;
        int col = scol ^ ((row & 7) * 8);
        srcoff[c] = row * K + col;
        dstoff[c] = chunk * 512;
    }

    f32x4 zero = {0.f, 0.f, 0.f, 0.f};
    f32x4 acc[4][4];
#pragma unroll
    for (int mi = 0; mi < 4; ++mi)
#pragma unroll
        for (int ni = 0; ni < 4; ++ni) acc[mi][ni] = zero;

    const unsigned short* Ab = A + (size_t)m0 * K;
    const unsigned short* Bb = Bt + (size_t)n0 * K;

#pragma unroll
    for (int c = 0; c < 4; ++c) {
        __builtin_amdgcn_global_load_lds((as1_ushort*)(Ab + srcoff[c]),
                                         (as3_ushort*)&Alds[0][dstoff[c]], 16, 0, 0);
        __builtin_amdgcn_global_load_lds((as1_ushort*)(Bb + srcoff[c]),
                                         (as3_ushort*)&Blds[0][dstoff[c]], 16, 0, 0);
    }
    asm volatile("s_waitcnt vmcnt(0)" ::: "memory");
    __syncthreads();

    int nk = K >> 6;
    for (int kt = 0; kt < nk; ++kt) {
        int cur = kt & 1;
        if (kt + 1 < nk) {
            int koff = (kt + 1) * 64;
#pragma unroll
            for (int c = 0; c < 4; ++c) {
                __builtin_amdgcn_global_load_lds((as1_ushort*)(Ab + srcoff[c] + koff),
                                                 (as3_ushort*)&Alds[cur ^ 1][dstoff[c]], 16, 0, 0);
                __builtin_amdgcn_global_load_lds((as1_ushort*)(Bb + srcoff[c] + koff),
                                                 (as3_ushort*)&Blds[cur ^ 1][dstoff[c]], 16, 0, 0);
            }
        }
#pragma unroll
        for (int ka = 0; ka < 2; ++ka) {
            bf16x8 af[4], bfr[4];
#pragma unroll
            for (int mi = 0; mi < 4; ++mi) {
                int arow = wm + mi * 16 + cidx;
                af[mi] = *reinterpret_cast<bf16x8*>(
                    &Alds[cur][arow * 64 + ((ka * 32 + quad * 8) ^ ((arow & 7) * 8))]);
            }
#pragma unroll
            for (int ni = 0; ni < 4; ++ni) {
                int brow = wn + ni * 16 + cidx;
                bfr[ni] = *reinterpret_cast<bf16x8*>(
                    &Blds[cur][brow * 64 + ((ka * 32 + quad * 8) ^ ((brow & 7) * 8))]);
            }
#pragma unroll
            for (int mi = 0; mi < 4; ++mi)
#pragma unroll
                for (int ni = 0; ni < 4; ++ni)
                    acc[mi][ni] = __builtin_amdgcn_mfma_f32_16x16x32_bf16(af[mi], bfr[ni],
                                                                          acc[mi][ni], 0, 0, 0);
        }
        asm volatile("s_waitcnt vmcnt(0)" ::: "memory");
        __syncthreads();
    }
#pragma unroll
    for (int mi = 0; mi < 4; ++mi)
#pragma unroll
        for (int ni = 0; ni < 4; ++ni)
#pragma unroll
            for (int i = 0; i < 4; ++i) {
                int row = m0 + wm + mi * 16 + quad * 4 + i;
                int col = n0 + wn + ni * 16 + cidx;
                C[(size_t)row * N + col] = acc[mi][ni][i];
            }
}

// ---------- fused QKV GEMM (BK=64, swizzled, double-buffered, XCD-swizzled) ----------
__global__ __launch_bounds__(256) void gemm_qkv(const unsigned short* __restrict__ A,
                                                const unsigned short* __restrict__ Bt,
                                                const int* __restrict__ pos_ids,
                                                const float2* __restrict__ cs,
                                                unsigned short* __restrict__ q_p,
                                                unsigned short* __restrict__ k_p,
                                                unsigned short* __restrict__ v_p) {
    __shared__ unsigned short Alds[2][128 * 64];
    __shared__ unsigned short Blds[2][128 * 64];
    int t = threadIdx.x;
    int lane = t & 63, w = t >> 6;
    int bx, by;
    xcd_swizzle(bx, by);
    int m0 = by * 128, n0 = bx * 128;
    int wm = (w >> 1) * 64, wn = (w & 1) * 64;
    int cidx = lane & 15, quad = lane >> 4;
    int srow = lane >> 3, scol = (lane & 7) * 8;

    int srcoff[4], dstoff[4];
#pragma unroll
    for (int c = 0; c < 4; ++c) {
        int chunk = w + c * 4;
        int row = chunk * 8 + srow;
        int col = scol ^ ((row & 7) * 8);
        srcoff[c] = row * HIDN + col;
        dstoff[c] = chunk * 512;
    }

    f32x4 zero = {0.f, 0.f, 0.f, 0.f};
    f32x4 acc[4][4];
#pragma unroll
    for (int mi = 0; mi < 4; ++mi)
#pragma unroll
        for (int ni = 0; ni < 4; ++ni) acc[mi][ni] = zero;

    const unsigned short* Ab = A + (size_t)m0 * HIDN;
    const unsigned short* Bb = Bt + (size_t)n0 * HIDN;

#pragma unroll
    for (int c = 0; c < 4; ++c) {
        __builtin_amdgcn_global_load_lds((as1_ushort*)(Ab + srcoff[c]),
                                         (as3_ushort*)&Alds[0][dstoff[c]], 16, 0, 0);
        __builtin_amdgcn_global_load_lds((as1_ushort*)(Bb + srcoff[c]),
                                         (as3_ushort*)&Blds[0][dstoff[c]], 16, 0, 0);
    }
    asm volatile("s_waitcnt vmcnt(0)" ::: "memory");
    __syncthreads();

    const int nk = HIDN >> 6;
    for (int kt = 0; kt < nk; ++kt) {
        int cur = kt & 1;
        if (kt + 1 < nk) {
            int koff = (kt + 1) * 64;
#pragma unroll
            for (int c = 0; c < 4; ++c) {
                __builtin_amdgcn_global_load_lds((as1_ushort*)(Ab + srcoff[c] + koff),
                                                 (as3_ushort*)&Alds[cur ^ 1][dstoff[c]], 16, 0, 0);
                __builtin_amdgcn_global_load_lds((as1_ushort*)(Bb + srcoff[c] + koff),
                                                 (as3_ushort*)&Blds[cur ^ 1][dstoff[c]], 16, 0, 0);
            }
        }
#pragma unroll
        for (int ka = 0; ka < 2; ++ka) {
            bf16x8 af[4], bfr[4];
#pragma unroll
            for (int mi = 0; mi < 4; ++mi) {
                int arow = wm + mi * 16 + cidx;
                af[mi] = *reinterpret_cast<bf16x8*>(
                    &Alds[cur][arow * 64 + ((ka * 32 + quad * 8) ^ ((arow & 7) * 8))]);
            }
#pragma unroll
            for (int ni = 0; ni < 4; ++ni) {
                int brow = wn + ni * 16 + cidx;
                bfr[ni] = *reinterpret_cast<bf16x8*>(
                    &Blds[cur][brow * 64 + ((ka * 32 + quad * 8) ^ ((brow & 7) * 8))]);
            }
#pragma unroll
            for (int mi = 0; mi < 4; ++mi)
#pragma unroll
                for (int ni = 0; ni < 4; ++ni)
                    acc[mi][ni] = __builtin_amdgcn_mfma_f32_16x16x32_bf16(af[mi], bfr[ni],
                                                                          acc[mi][ni], 0, 0, 0);
        }
        asm volatile("s_waitcnt vmcnt(0)" ::: "memory");
        __syncthreads();
    }

    // ---- fused epilogue ----
    int colbase = n0 + wn;   // multiple of 64 -> exactly one head
    if (colbase >= NH * HD + NKV * HD) {        // V segment: plain pack
        int h = (colbase - (NH * HD + NKV * HD)) >> 6;
#pragma unroll
        for (int mi = 0; mi < 4; ++mi)
#pragma unroll
            for (int i = 0; i < 4; ++i) {
                int row = m0 + wm + mi * 16 + quad * 4 + i;
                int b = row >> 11, s = row & 2047;
                size_t base = ((size_t)(b * NKV + h) * SS + s) * 64;
#pragma unroll
                for (int ni = 0; ni < 4; ++ni)
                    v_p[base + ni * 16 + cidx] = f2bf(acc[mi][ni][i]);
            }
    } else {
        bool isQ = colbase < NH * HD;
        unsigned short* dst = isQ ? q_p : k_p;
        int h = isQ ? (colbase >> 6) : ((colbase - NH * HD) >> 6);
        int H = isQ ? NH : NKV;
        float scl = isQ ? (0.125f * LOG2E) : 1.0f;  // Q pre-scaled; log2-domain softmax
#pragma unroll
        for (int mi = 0; mi < 4; ++mi)
#pragma unroll
            for (int i = 0; i < 4; ++i) {
                int row = m0 + wm + mi * 16 + quad * 4 + i;
                int b = row >> 11, s = row & 2047;
                int pos = pos_ids[row];
                float2 c1 = cs[pos * 32 + cidx];
                float2 c2 = cs[pos * 32 + 16 + cidx];
                size_t base = ((size_t)(b * H + h) * SS + s) * 64;
                float x10 = acc[mi][0][i], x20 = acc[mi][2][i];
                float x11 = acc[mi][1][i], x21 = acc[mi][3][i];
                dst[base + cidx]       = f2bf((x10 * c1.x - x20 * c1.y) * scl);
                dst[base + 32 + cidx]  = f2bf((x20 * c1.x + x10 * c1.y) * scl);
                dst[base + 16 + cidx]  = f2bf((x11 * c2.x - x21 * c2.y) * scl);
                dst[base + 48 + cidx]  = f2bf((x21 * c2.x + x11 * c2.y) * scl);
            }
    }
}

// ---------- split-KV flash attention: chunks of <=12 tiles, balanced split ----------
// C(qt)=ceil((qt+1)/12) in {1,2,3}; NCHUNK=60. qt<12: single chunk, direct write.
// Chunk c covers tiles [c*ntot/C, (c+1)*ntot/C).
#define TRR(dst, ADDR, OFF) asm volatile("ds_read_b64_tr_b16 %0, %1 offset:" #OFF \
                                         : "=v"(dst) : "v"(ADDR))

__global__ __launch_bounds__(256, 4) void k_attn(const unsigned short* __restrict__ Qp,
                                                 const unsigned short* __restrict__ Kp,
                                                 const unsigned short* __restrict__ Vp,
                                                 unsigned short* __restrict__ part_acc,
                                                 float* __restrict__ part_ml,
                                                 unsigned short* __restrict__ a_out) {
    int bxr = NCHUNK - 1 - (int)blockIdx.x;   // heavy (large qt) first
    int h = blockIdx.y, b = blockIdx.z;
    int kvh = h >> 2;
    // decode bxr -> (g, qt, c): g0 = qt 0..11 (12), g1 = qt 12..23 x2 (24), g2 = qt 24..31 x3 (24)
    int g, qt, c;
    if (bxr < 12)      { g = 0; qt = bxr; c = 0; }
    else if (bxr < 36) { g = 1; int idx = bxr - 12; qt = 12 + (idx >> 1); c = idx & 1; }
    else               { g = 2; int idx = bxr - 36; qt = 24 + idx / 3; c = idx % 3; }
    int p = (b * NH + h) * NCHUNK + bxr;
    int qbase = qt * 64;
    int ntot = qt + 1, C = g + 1;
    int t0 = c * ntot / C;
    int nt = (c + 1) * ntot / C - t0;
    int ck0 = t0 * 64;

    int t = threadIdx.x, lane = t & 63, w = t >> 6;
    int cidx = lane & 15, quad = lane >> 4;
    int qrow0 = qbase + w * 16;

    const unsigned short* qptr  = Qp + ((size_t)(b * NH + h) * SS + qrow0) * HD;
    const unsigned short* kbase = Kp + (((size_t)(b * NKV + kvh) * SS) + ck0) * HD;
    const unsigned short* vbase = Vp + (((size_t)(b * NKV + kvh) * SS) + ck0) * HD;

    __shared__ unsigned short Klds[2 * 4096];    // 2 x 8KB tiled K [ht][ka][quad][cidx][8]
    __shared__ unsigned short Vt[2 * 4096];      // 2 x 8KB tiled V [d16][kv4][4][16]
    __shared__ unsigned short Pt[4][64 * 16];    // per-wave P^T

    const unsigned short* ksrc[2];
    const unsigned short* vsrc[2];
#pragma unroll
    for (int i = 0; i < 2; ++i) {
        int o = (w * 2 + i) * 512 + lane * 8;
        int kh = o >> 10, ka_ = (o >> 9) & 1, kq = (o >> 7) & 3, kc = (o >> 3) & 15;
        ksrc[i] = kbase + (kh * 16 + kc) * HD + ka_ * 32 + kq * 8;
        int r = o & 1023;
        int kv = ((r >> 6) << 2) | ((r >> 4) & 3);
        int d  = ((o >> 10) << 4) | (r & 15);
        vsrc[i] = vbase + kv * HD + d;
    }

    bf16x8 qa[2];
#pragma unroll
    for (int ka = 0; ka < 2; ++ka)
        qa[ka] = *reinterpret_cast<const bf16x8*>(qptr + (size_t)cidx * HD + ka * 32 + quad * 8);

    bf16x8 ones;
    {
        unsigned short ob = 0x3F80;  // bf16 1.0
        u16x8 ov;
#pragma unroll
        for (int j = 0; j < 8; ++j) ov[j] = ob;
        __builtin_memcpy(&ones, &ov, 16);
    }

    f32x4 zero = {0.f, 0.f, 0.f, 0.f};
    f32x4 acc[4], acc_l = zero;
    float m_run[4];
#pragma unroll
    for (int i = 0; i < 4; ++i) { acc[i] = zero; m_run[i] = -1e30f; }

    // prologue: stage K0,V0 into buf 0
#pragma unroll
    for (int i = 0; i < 2; ++i) {
        __builtin_amdgcn_global_load_lds((as1_ushort*)ksrc[i],
                                         (as3_ushort*)&Klds[(w * 2 + i) * 512], 16, 0, 0);
        __builtin_amdgcn_global_load_lds((as1_ushort*)vsrc[i],
                                         (as3_ushort*)&Vt[(w * 2 + i) * 512], 16, 0, 0);
    }
    asm volatile("s_waitcnt vmcnt(0)" ::: "memory");
    __syncthreads();

    unsigned vtb  = (unsigned)(uintptr_t)(as3_ushort*)&Vt[0];
    unsigned va_base = vtb + (unsigned)(quad * 256 + cidx * 8);
    unsigned ptb  = (unsigned)(uintptr_t)(as3_ushort*)&Pt[w][0];
    unsigned va_p = ptb + (unsigned)(quad * 256 + cidx * 8);
    char* pwr = (char*)&Pt[w][0] + cidx * 32 + quad * 8;

    for (int it = 0; it < nt; ++it) {
        int cur = it & 1;
        int kvb = ck0 + it * 64;

        // ---- issue next-tile K+V prefetch ----
        if (it + 1 < nt) {
            size_t nv = (size_t)(it + 1) * 64 * HD;
#pragma unroll
            for (int i = 0; i < 2; ++i) {
                __builtin_amdgcn_global_load_lds(
                    (as1_ushort*)(ksrc[i] + nv),
                    (as3_ushort*)&Klds[(cur ^ 1) * 4096 + (w * 2 + i) * 512], 16, 0, 0);
                __builtin_amdgcn_global_load_lds(
                    (as1_ushort*)(vsrc[i] + nv),
                    (as3_ushort*)&Vt[(cur ^ 1) * 4096 + (w * 2 + i) * 512], 16, 0, 0);
            }
        }

        // ---- QK^T from LDS ----
        bf16x8 kb[4][2];
#pragma unroll
        for (int ht = 0; ht < 4; ++ht)
#pragma unroll
            for (int ka = 0; ka < 2; ++ka)
                kb[ht][ka] = *reinterpret_cast<bf16x8*>(
                    &Klds[cur * 4096 + ht * 1024 + ka * 512 + quad * 128 + cidx * 8]);
        f32x4 sc[4];
#pragma unroll
        for (int ht = 0; ht < 4; ++ht) {
            f32x4 cacc = zero;
            cacc = __builtin_amdgcn_mfma_f32_16x16x32_bf16(qa[0], kb[ht][0], cacc, 0, 0, 0);
            cacc = __builtin_amdgcn_mfma_f32_16x16x32_bf16(qa[1], kb[ht][1], cacc, 0, 0, 0);
            sc[ht] = cacc;
        }

        // ---- V tr-reads hoisted (V[cur] drained last iter; latency hides under softmax) ----
        unsigned va = va_base + (unsigned)(cur * 8192);
        u32x2 tv[4][4];
        TRR(tv[0][0], va, 0);    TRR(tv[0][1], va, 128);
        TRR(tv[0][2], va, 1024); TRR(tv[0][3], va, 1152);
        TRR(tv[1][0], va, 2048); TRR(tv[1][1], va, 2176);
        TRR(tv[1][2], va, 3072); TRR(tv[1][3], va, 3200);
        TRR(tv[2][0], va, 4096); TRR(tv[2][1], va, 4224);
        TRR(tv[2][2], va, 5120); TRR(tv[2][3], va, 5248);
        TRR(tv[3][0], va, 6144); TRR(tv[3][1], va, 6272);
        TRR(tv[3][2], va, 7168); TRR(tv[3][3], va, 7296);

        // ---- causal mask (diagonal tile only) ----
        if (kvb + 63 > qrow0) {
#pragma unroll
            for (int ht = 0; ht < 4; ++ht)
#pragma unroll
                for (int i = 0; i < 4; ++i)
                    if (kvb + ht * 16 + cidx > qrow0 + quad * 4 + i) sc[ht][i] = -1e30f;
        }

        // ---- row max via DPP rotations ----
        float mx[4];
#pragma unroll
        for (int i = 0; i < 4; ++i) {
            mx[i] = fmaxf(fmaxf(sc[0][i], sc[1][i]), fmaxf(sc[2][i], sc[3][i]));
            mx[i] = rowmax16_dpp(mx[i]);
        }

        // ---- defer-max (T13, log2 domain: threshold 11.5 bits ~ 8 nats) ----
        bool need = false;
#pragma unroll
        for (int i = 0; i < 4; ++i) need |= (mx[i] > m_run[i] + 11.5f);
        if (__any(need)) {
#pragma unroll
            for (int i = 0; i < 4; ++i) {
                float mnew = fmaxf(m_run[i], mx[i]);
                float scl = exp2_hw(m_run[i] - mnew);
                m_run[i] = mnew;
#pragma unroll
                for (int dt = 0; dt < 4; ++dt) acc[dt][i] *= scl;
                acc_l[i] *= scl;
            }
        }
#pragma unroll
        for (int i = 0; i < 4; ++i)
#pragma unroll
            for (int ht = 0; ht < 4; ++ht) sc[ht][i] = exp2_hw(sc[ht][i] - m_run[i]);

        // ---- P^T -> LDS (cvt_pk + 4x ds_write_b64), then P tr-reads ----
#pragma unroll
        for (int ht = 0; ht < 4; ++ht) {
            u32x2 pk;
            pk[0] = cvt_pk_bf16(sc[ht][0], sc[ht][1]);
            pk[1] = cvt_pk_bf16(sc[ht][2], sc[ht][3]);
            *reinterpret_cast<u32x2*>(pwr + ht * 512) = pk;
        }
        asm volatile("" ::: "memory");
        u32x2 pt_[4];
        TRR(pt_[0], va_p, 0);    TRR(pt_[1], va_p, 128);
        TRR(pt_[2], va_p, 1024); TRR(pt_[3], va_p, 1152);
        asm volatile("s_waitcnt lgkmcnt(0)" ::: "memory");
        __builtin_amdgcn_sched_barrier(0);

        union { u32x2 a[2]; bf16x8 v; } up0, up1;
        up0.a[0] = pt_[0]; up0.a[1] = pt_[1];
        up1.a[0] = pt_[2]; up1.a[1] = pt_[3];
        bf16x8 pa0 = up0.v, pa1 = up1.v;

        // ---- all MFMAs in one cluster ----
        __builtin_amdgcn_s_setprio(1);
        acc_l = __builtin_amdgcn_mfma_f32_16x16x32_bf16(pa0, ones, acc_l, 0, 0, 0);
        acc_l = __builtin_amdgcn_mfma_f32_16x16x32_bf16(pa1, ones, acc_l, 0, 0, 0);
#pragma unroll
        for (int dt = 0; dt < 4; ++dt) {
            union { u32x2 a[2]; bf16x8 v; } u0, u1;
            u0.a[0] = tv[dt][0]; u0.a[1] = tv[dt][1];
            u1.a[0] = tv[dt][2]; u1.a[1] = tv[dt][3];
            acc[dt] = __builtin_amdgcn_mfma_f32_16x16x32_bf16(pa0, u0.v, acc[dt], 0, 0, 0);
            acc[dt] = __builtin_amdgcn_mfma_f32_16x16x32_bf16(pa1, u1.v, acc[dt], 0, 0, 0);
        }
        __builtin_amdgcn_s_setprio(0);

        // prefetch had the whole tile to land; drain + sync
        asm volatile("s_waitcnt vmcnt(0)" ::: "memory");
        __syncthreads();
    }

    if (g == 0) {
        // single-chunk (qt<12): normalize and write attention output directly
        float rl[4];
#pragma unroll
        for (int i = 0; i < 4; ++i) rl[i] = 1.f / acc_l[i];
#pragma unroll
        for (int dt = 0; dt < 4; ++dt)
#pragma unroll
            for (int i = 0; i < 4; ++i) {
                int row = qrow0 + quad * 4 + i;
                size_t o = ((size_t)(b * SS) + row) * HIDN + h * HD + dt * 16 + cidx;
                a_out[o] = f2bf(acc[dt][i] * rl[i]);
            }
    } else {
        // multi-chunk: write unnormalized partials (m in log2 units)
#pragma unroll
        for (int dt = 0; dt < 4; ++dt)
#pragma unroll
            for (int i = 0; i < 4; ++i) {
                int row = w * 16 + quad * 4 + i;
                part_acc[((size_t)p * 64 + row) * 64 + dt * 16 + cidx] = f2bf(acc[dt][i]);
            }
        if (cidx == 0) {
#pragma unroll
            for (int i = 0; i < 4; ++i) {
                int row = w * 16 + quad * 4 + i;
                part_ml[((size_t)p * 64 + row) * 2 + 0] = m_run[i];
                part_ml[((size_t)p * 64 + row) * 2 + 1] = acc_l[i];
            }
        }
    }
}

// ---------- combine partials (rows s>=768 only, C in {2,3}) -> a_out ----------
__global__ __launch_bounds__(256) void k_combine(const unsigned short* __restrict__ part_acc,
                                                 const float* __restrict__ part_ml,
                                                 unsigned short* __restrict__ a_out) {
    int idx = blockIdx.x * 256 + threadIdx.x;  // BB*(SS-768)*NH*HD threads
    int d = idx & 63;
    int tmp = idx >> 6;
    int h = tmp % NH;
    int m2 = tmp / NH;               // [0, BB*(SS-768))
    int b = m2 / (SS - 768);
    int s = 768 + m2 % (SS - 768);
    int qt = s >> 6, row = s & 63;   // qt in [12,32)
    int g = (qt < 24) ? 1 : 2;
    int C = g + 1;
    int off = (g == 1) ? (12 + (qt - 12) * 2) : (36 + (qt - 24) * 3);
    int pb = (b * NH + h) * NCHUNK + off;

    float2 ml[3];
    float M = -1e30f;
#pragma unroll
    for (int cc = 0; cc < 3; ++cc) {
        if (cc < C) {
            ml[cc] = *reinterpret_cast<const float2*>(&part_ml[((size_t)(pb + cc) * 64 + row) * 2]);
            M = fmaxf(M, ml[cc].x);
        } else {
            ml[cc] = make_float2(-1e30f, 0.f);
        }
    }
    float L = 0.f, O = 0.f;
#pragma unroll
    for (int cc = 0; cc < 3; ++cc) {
        if (cc < C) {
            float wgt = exp2_hw(ml[cc].x - M);
            L += ml[cc].y * wgt;
            O += bf2f(part_acc[((size_t)(pb + cc) * 64 + row) * 64 + d]) * wgt;
        }
    }
    a_out[((size_t)(b * SS) + s) * HIDN + h * 64 + d] = f2bf(O / L);
}

extern "C" void kernel_launch(void* const* d_in, const int* in_sizes, int n_in,
                              void* d_out, int out_size, void* d_ws, size_t ws_size,
                              hipStream_t stream) {
    (void)in_sizes; (void)n_in; (void)out_size; (void)ws_size;
    const float* h_f  = (const float*)d_in[0];
    const int*   pos  = (const int*)d_in[1];
    const float* Wq_f = (const float*)d_in[2];
    const float* Wk_f = (const float*)d_in[3];
    const float* Wv_f = (const float*)d_in[4];
    const float* Wo_f = (const float*)d_in[5];
    float* out = (float*)d_out;

    char* ws = (char*)d_ws;
    size_t off = 0;
    auto alloc = [&](size_t bytes) -> void* {
        void* p = ws + off;
        off += (bytes + 255) & ~(size_t)255;
        return p;
    };
    // region 0: h_bf (12.58MB, dead after QKV gemm) overlaid by part_acc (23.6MB)
    unsigned short* region0 = (unsigned short*)alloc((size_t)48 * NCHUNK * 64 * 64 * 2);
    unsigned short* h_bf     = region0;
    unsigned short* part_acc = region0;
    unsigned short* qkv_w  = (unsigned short*)alloc((size_t)NQKV * HIDN * 2);
    unsigned short* Wo_bf  = (unsigned short*)alloc((size_t)HIDN * NH * HD * 2);
    unsigned short* q_p    = (unsigned short*)alloc((size_t)MTOT * NH * HD * 2);
    unsigned short* k_p    = (unsigned short*)alloc((size_t)MTOT * NKV * HD * 2);
    unsigned short* v_p    = (unsigned short*)alloc((size_t)MTOT * NKV * HD * 2);
    unsigned short* a_out  = (unsigned short*)alloc((size_t)MTOT * HIDN * 2);
    float2* cs = (float2*)alloc((size_t)SS * 32 * 8);
    float* part_ml = (float*)alloc((size_t)BB * NH * NCHUNK * 64 * 2 * 4);

    // merged prep: hidden cast + weight casts + cos/sin table
    {
        int nH = MTOT * HIDN / 4;
        int nW = 2 * (HIDN * HIDN / 4) + 2 * (NKV * HD * HIDN / 4);
        int total = nH + nW + SS * 32;   // divisible by 256
        k_prep<<<total / 256, 256, 0, stream>>>(h_f, Wq_f, Wk_f, Wv_f, Wo_f,
                                                h_bf, qkv_w, Wo_bf, cs);
    }

    // fused QKV projection + RoPE + pack
    gemm_qkv<<<dim3(NQKV / 128, MTOT / 128), 256, 0, stream>>>(
        h_bf, qkv_w, pos, cs, q_p, k_p, v_p);

    // split-KV attention + combine (part_acc overlays the now-dead h_bf region)
    k_attn<<<dim3(NCHUNK, NH, BB), 256, 0, stream>>>(q_p, k_p, v_p, part_acc, part_ml, a_out);
    {
        int total = BB * (SS - 768) * NH * HD;   // 2*1280*24*64 = 3932160, /256 = 15360
        k_combine<<<total / 256, 256, 0, stream>>>(part_acc, part_ml, a_out);
    }

    // output projection
    gemm_bt<float><<<dim3(HIDN / 128, MTOT / 128), 256, 0, stream>>>(
        a_out, Wo_bf, out, HIDN, HIDN);
}